// Round 1
// baseline (1908.824 us; speedup 1.0000x reference)
//
#include <hip/hip_runtime.h>
#include <hip/hip_bf16.h>

#define SLOPE 0.2f
#define EPSV 1e-16f

// ---------------- GEMM1: h1 = x @ W1  [N,128]x[128,128] + fused a_s1/a_d1 ----------------
// 256 threads, 32 rows/block, k-tiled by 32. Each thread: 4 rows x 4 cols.
__global__ __launch_bounds__(256) void gemm1_kernel(
    const float* __restrict__ x, const float* __restrict__ W,
    const float* __restrict__ att_src, const float* __restrict__ att_dst,
    float* __restrict__ h1, float* __restrict__ as1, float* __restrict__ ad1, int N)
{
    __shared__ __align__(16) float Wsh[32 * 128];
    __shared__ __align__(16) float xT[32 * 36];   // [kl][row], padded stride 36
    const int t  = threadIdx.x;
    const int cg = t & 31;        // cols cg*4 .. cg*4+3
    const int rg = t >> 5;        // rows rg*4 .. rg*4+3  (8 groups -> 32 rows)
    const int row0 = blockIdx.x * 32;

    float acc[4][4] = {};
    for (int kk = 0; kk < 128; kk += 32) {
        for (int i = t; i < 32 * 128; i += 256) {
            int kl = i >> 7, c = i & 127;
            Wsh[i] = W[(kk + kl) * 128 + c];
        }
        for (int i = t; i < 32 * 32; i += 256) {
            int r = i >> 5, kl = i & 31;
            int row = row0 + r;
            xT[kl * 36 + r] = (row < N) ? x[(size_t)row * 128 + kk + kl] : 0.0f;
        }
        __syncthreads();
        #pragma unroll
        for (int kl = 0; kl < 32; ++kl) {
            float xv[4], wv[4];
            *(float4*)xv = *(const float4*)&xT[kl * 36 + rg * 4];
            *(float4*)wv = *(const float4*)&Wsh[kl * 128 + cg * 4];
            #pragma unroll
            for (int r = 0; r < 4; ++r)
                #pragma unroll
                for (int c = 0; c < 4; ++c)
                    acc[r][c] = fmaf(xv[r], wv[c], acc[r][c]);
        }
        __syncthreads();
    }

    float asv[4], adv[4];
    *(float4*)asv = *(const float4*)&att_src[cg * 4];
    *(float4*)adv = *(const float4*)&att_dst[cg * 4];
    const int head = cg >> 2;  // 4 col-groups per head (16 cols/head)

    #pragma unroll
    for (int r = 0; r < 4; ++r) {
        int row = row0 + rg * 4 + r;
        float s = acc[r][0]*asv[0] + acc[r][1]*asv[1] + acc[r][2]*asv[2] + acc[r][3]*asv[3];
        float d = acc[r][0]*adv[0] + acc[r][1]*adv[1] + acc[r][2]*adv[2] + acc[r][3]*adv[3];
        s += __shfl_xor(s, 1, 4); s += __shfl_xor(s, 2, 4);
        d += __shfl_xor(d, 1, 4); d += __shfl_xor(d, 2, 4);
        if (row < N) {
            *(float4*)&h1[(size_t)row * 128 + cg * 4] =
                make_float4(acc[r][0], acc[r][1], acc[r][2], acc[r][3]);
            if ((cg & 3) == 0) {
                as1[row * 8 + head] = s;
                ad1[row * 8 + head] = d;
            }
        }
    }
}

// ---------------- GEMM2: h2 = h @ W2 [N,128]x[128,64] + fused a_s2/a_d2 + d_out=b2 ----------------
// 256 threads, 64 rows/block, k-tiled by 32. Each thread: 4 rows x 4 cols.
__global__ __launch_bounds__(256) void gemm2_kernel(
    const float* __restrict__ h, const float* __restrict__ W,
    const float* __restrict__ att_src, const float* __restrict__ att_dst,
    const float* __restrict__ b2,
    float* __restrict__ h2, float* __restrict__ as2, float* __restrict__ ad2,
    float* __restrict__ out, int N)
{
    __shared__ __align__(16) float Wsh[32 * 64];
    __shared__ __align__(16) float xT[32 * 68];   // [kl][row], padded stride 68
    const int t  = threadIdx.x;
    const int cg = t & 15;        // cols cg*4 .. cg*4+3 (64 cols)
    const int rg = t >> 4;        // rows rg*4 .. rg*4+3 (16 groups -> 64 rows)
    const int row0 = blockIdx.x * 64;

    float acc[4][4] = {};
    for (int kk = 0; kk < 128; kk += 32) {
        for (int i = t; i < 32 * 64; i += 256) {
            int kl = i >> 6, c = i & 63;
            Wsh[i] = W[(kk + kl) * 64 + c];
        }
        for (int i = t; i < 64 * 32; i += 256) {
            int r = i >> 5, kl = i & 31;
            int row = row0 + r;
            xT[kl * 68 + r] = (row < N) ? h[(size_t)row * 128 + kk + kl] : 0.0f;
        }
        __syncthreads();
        #pragma unroll
        for (int kl = 0; kl < 32; ++kl) {
            float xv[4], wv[4];
            *(float4*)xv = *(const float4*)&xT[kl * 68 + rg * 4];
            *(float4*)wv = *(const float4*)&Wsh[kl * 64 + cg * 4];
            #pragma unroll
            for (int r = 0; r < 4; ++r)
                #pragma unroll
                for (int c = 0; c < 4; ++c)
                    acc[r][c] = fmaf(xv[r], wv[c], acc[r][c]);
        }
        __syncthreads();
    }

    float asv[4], adv[4], bv[4];
    *(float4*)asv = *(const float4*)&att_src[cg * 4];
    *(float4*)adv = *(const float4*)&att_dst[cg * 4];
    *(float4*)bv  = *(const float4*)&b2[cg * 4];

    #pragma unroll
    for (int r = 0; r < 4; ++r) {
        int row = row0 + rg * 4 + r;
        float s = acc[r][0]*asv[0] + acc[r][1]*asv[1] + acc[r][2]*asv[2] + acc[r][3]*asv[3];
        float d = acc[r][0]*adv[0] + acc[r][1]*adv[1] + acc[r][2]*adv[2] + acc[r][3]*adv[3];
        #pragma unroll
        for (int off = 1; off < 16; off <<= 1) {
            s += __shfl_xor(s, off, 16);
            d += __shfl_xor(d, off, 16);
        }
        if (row < N) {
            *(float4*)&h2[(size_t)row * 64 + cg * 4] =
                make_float4(acc[r][0], acc[r][1], acc[r][2], acc[r][3]);
            *(float4*)&out[(size_t)row * 64 + cg * 4] = make_float4(bv[0], bv[1], bv[2], bv[3]);
            if (cg == 0) { as2[row] = s; ad2[row] = d; }
        }
    }
}

// ---------------- edge pass: softmax denominators, layer 1 (8 heads) ----------------
__global__ __launch_bounds__(256) void edge_denom1_kernel(
    const int* __restrict__ ei, const float* __restrict__ as1, const float* __restrict__ ad1,
    float* __restrict__ denom1, int E)
{
    int e = blockIdx.x * 256 + threadIdx.x;
    if (e >= E) return;
    int s = ei[e], d = ei[E + e];
    float4 s0 = *(const float4*)&as1[s * 8];
    float4 s1 = *(const float4*)&as1[s * 8 + 4];
    float4 d0 = *(const float4*)&ad1[d * 8];
    float4 d1 = *(const float4*)&ad1[d * 8 + 4];
    float v[8] = { s0.x + d0.x, s0.y + d0.y, s0.z + d0.z, s0.w + d0.w,
                   s1.x + d1.x, s1.y + d1.y, s1.z + d1.z, s1.w + d1.w };
    #pragma unroll
    for (int h = 0; h < 8; ++h) {
        float ev = v[h];
        ev = ev > 0.0f ? ev : SLOPE * ev;
        atomicAdd(&denom1[d * 8 + h], __expf(ev));
    }
}

// ---------------- edge pass: weighted scatter, layer 1 (128 ch/edge) ----------------
__global__ __launch_bounds__(256) void edge_scatter1_kernel(
    const int* __restrict__ ei, const float* __restrict__ as1, const float* __restrict__ ad1,
    const float* __restrict__ denom1, const float* __restrict__ h1,
    float* __restrict__ out1, int E)
{
    int gid = blockIdx.x * 256 + threadIdx.x;
    int e = gid >> 7;
    if (e >= E) return;
    int ch = gid & 127, hh = ch >> 4;
    int s = ei[e], d = ei[E + e];
    float ev = as1[s * 8 + hh] + ad1[d * 8 + hh];
    ev = ev > 0.0f ? ev : SLOPE * ev;
    float alpha = __expf(ev) / (denom1[d * 8 + hh] + EPSV);
    atomicAdd(&out1[(size_t)d * 128 + ch], alpha * h1[(size_t)s * 128 + ch]);
}

// ---------------- ELU + bias (in place) ----------------
__global__ __launch_bounds__(256) void elu_kernel(float* __restrict__ h,
                                                  const float* __restrict__ b1, int n4)
{
    int i = blockIdx.x * 256 + threadIdx.x;
    if (i >= n4) return;
    float4 v = ((float4*)h)[i];
    float4 b = ((const float4*)b1)[i & 31];
    v.x += b.x; v.y += b.y; v.z += b.z; v.w += b.w;
    v.x = v.x > 0.0f ? v.x : expm1f(v.x);
    v.y = v.y > 0.0f ? v.y : expm1f(v.y);
    v.z = v.z > 0.0f ? v.z : expm1f(v.z);
    v.w = v.w > 0.0f ? v.w : expm1f(v.w);
    ((float4*)h)[i] = v;
}

// ---------------- edge pass: denominators, layer 2 (1 head) ----------------
__global__ __launch_bounds__(256) void edge_denom2_kernel(
    const int* __restrict__ ei, const float* __restrict__ as2, const float* __restrict__ ad2,
    float* __restrict__ denom2, int E)
{
    int e = blockIdx.x * 256 + threadIdx.x;
    if (e >= E) return;
    int s = ei[e], d = ei[E + e];
    float ev = as2[s] + ad2[d];
    ev = ev > 0.0f ? ev : SLOPE * ev;
    atomicAdd(&denom2[d], __expf(ev));
}

// ---------------- edge pass: weighted scatter, layer 2 (64 ch/edge) ----------------
__global__ __launch_bounds__(256) void edge_scatter2_kernel(
    const int* __restrict__ ei, const float* __restrict__ as2, const float* __restrict__ ad2,
    const float* __restrict__ denom2, const float* __restrict__ h2,
    float* __restrict__ out, int E)
{
    int gid = blockIdx.x * 256 + threadIdx.x;
    int e = gid >> 6;
    if (e >= E) return;
    int ch = gid & 63;
    int s = ei[e], d = ei[E + e];
    float ev = as2[s] + ad2[d];
    ev = ev > 0.0f ? ev : SLOPE * ev;
    float alpha = __expf(ev) / (denom2[d] + EPSV);
    atomicAdd(&out[(size_t)d * 64 + ch], alpha * h2[(size_t)s * 64 + ch]);
}

extern "C" void kernel_launch(void* const* d_in, const int* in_sizes, int n_in,
                              void* d_out, int out_size, void* d_ws, size_t ws_size,
                              hipStream_t stream)
{
    const int N = in_sizes[0] / 128;
    const int E = in_sizes[1] / 2;

    const float* x        = (const float*)d_in[0];
    const int*   ei       = (const int*)  d_in[1];
    const float* W1       = (const float*)d_in[2];
    const float* att_src1 = (const float*)d_in[3];
    const float* att_dst1 = (const float*)d_in[4];
    const float* b1       = (const float*)d_in[5];
    const float* W2       = (const float*)d_in[6];
    const float* att_src2 = (const float*)d_in[7];
    const float* att_dst2 = (const float*)d_in[8];
    const float* b2       = (const float*)d_in[9];
    float* out = (float*)d_out;

    float* ws = (float*)d_ws;
    float* h1     = ws;                          // N*128
    float* hbuf   = h1     + (size_t)N * 128;    // N*128 (out1 accum -> elu'd h)
    float* denom1 = hbuf   + (size_t)N * 128;    // N*8
    float* denom2 = denom1 + (size_t)N * 8;      // N
    float* h2     = denom2 + (size_t)N;          // N*64
    float* as1    = h2     + (size_t)N * 64;     // N*8
    float* ad1    = as1    + (size_t)N * 8;      // N*8
    float* as2    = ad1    + (size_t)N * 8;      // N
    float* ad2    = as2    + (size_t)N;          // N

    // zero the accumulators (hbuf, denom1, denom2 are contiguous)
    hipMemsetAsync(hbuf, 0, (size_t)(N * 128 + N * 8 + N) * sizeof(float), stream);

    gemm1_kernel<<<(N + 31) / 32, 256, 0, stream>>>(x, W1, att_src1, att_dst1, h1, as1, ad1, N);
    edge_denom1_kernel<<<(E + 255) / 256, 256, 0, stream>>>(ei, as1, ad1, denom1, E);
    {
        long long tot = (long long)E * 128;
        edge_scatter1_kernel<<<(int)((tot + 255) / 256), 256, 0, stream>>>(
            ei, as1, ad1, denom1, h1, hbuf, E);
    }
    elu_kernel<<<(N * 32 + 255) / 256, 256, 0, stream>>>(hbuf, b1, N * 32);
    gemm2_kernel<<<(N + 63) / 64, 256, 0, stream>>>(hbuf, W2, att_src2, att_dst2, b2,
                                                    h2, as2, ad2, out, N);
    edge_denom2_kernel<<<(E + 255) / 256, 256, 0, stream>>>(ei, as2, ad2, denom2, E);
    {
        long long tot = (long long)E * 64;
        edge_scatter2_kernel<<<(int)((tot + 255) / 256), 256, 0, stream>>>(
            ei, as2, ad2, denom2, h2, out, E);
    }
}

// Round 2
// 788.425 us; speedup vs baseline: 2.4211x; 2.4211x over previous
//
#include <hip/hip_runtime.h>
#include <hip/hip_bf16.h>

#define SLOPE 0.2f
#define EPSV 1e-16f

// ---------------- GEMM1: h1 = x @ W1  [N,128]x[128,128] + fused a_s1/a_d1 ----------------
__global__ __launch_bounds__(256) void gemm1_kernel(
    const float* __restrict__ x, const float* __restrict__ W,
    const float* __restrict__ att_src, const float* __restrict__ att_dst,
    float* __restrict__ h1, float* __restrict__ as1, float* __restrict__ ad1, int N)
{
    __shared__ __align__(16) float Wsh[32 * 128];
    __shared__ __align__(16) float xT[32 * 36];
    const int t  = threadIdx.x;
    const int cg = t & 31;
    const int rg = t >> 5;
    const int row0 = blockIdx.x * 32;

    float acc[4][4] = {};
    for (int kk = 0; kk < 128; kk += 32) {
        for (int i = t; i < 32 * 128; i += 256) {
            int kl = i >> 7, c = i & 127;
            Wsh[i] = W[(kk + kl) * 128 + c];
        }
        for (int i = t; i < 32 * 32; i += 256) {
            int r = i >> 5, kl = i & 31;
            int row = row0 + r;
            xT[kl * 36 + r] = (row < N) ? x[(size_t)row * 128 + kk + kl] : 0.0f;
        }
        __syncthreads();
        #pragma unroll
        for (int kl = 0; kl < 32; ++kl) {
            float xv[4], wv[4];
            *(float4*)xv = *(const float4*)&xT[kl * 36 + rg * 4];
            *(float4*)wv = *(const float4*)&Wsh[kl * 128 + cg * 4];
            #pragma unroll
            for (int r = 0; r < 4; ++r)
                #pragma unroll
                for (int c = 0; c < 4; ++c)
                    acc[r][c] = fmaf(xv[r], wv[c], acc[r][c]);
        }
        __syncthreads();
    }

    float asv[4], adv[4];
    *(float4*)asv = *(const float4*)&att_src[cg * 4];
    *(float4*)adv = *(const float4*)&att_dst[cg * 4];
    const int head = cg >> 2;

    #pragma unroll
    for (int r = 0; r < 4; ++r) {
        int row = row0 + rg * 4 + r;
        float s = acc[r][0]*asv[0] + acc[r][1]*asv[1] + acc[r][2]*asv[2] + acc[r][3]*asv[3];
        float d = acc[r][0]*adv[0] + acc[r][1]*adv[1] + acc[r][2]*adv[2] + acc[r][3]*adv[3];
        s += __shfl_xor(s, 1, 4); s += __shfl_xor(s, 2, 4);
        d += __shfl_xor(d, 1, 4); d += __shfl_xor(d, 2, 4);
        if (row < N) {
            *(float4*)&h1[(size_t)row * 128 + cg * 4] =
                make_float4(acc[r][0], acc[r][1], acc[r][2], acc[r][3]);
            if ((cg & 3) == 0) {
                as1[row * 8 + head] = s;
                ad1[row * 8 + head] = d;
            }
        }
    }
}

// ---------------- GEMM2: h2 = h @ W2 [N,128]x[128,64] + fused a_s2/a_d2 ----------------
__global__ __launch_bounds__(256) void gemm2_kernel(
    const float* __restrict__ h, const float* __restrict__ W,
    const float* __restrict__ att_src, const float* __restrict__ att_dst,
    float* __restrict__ h2, float* __restrict__ as2, float* __restrict__ ad2, int N)
{
    __shared__ __align__(16) float Wsh[32 * 64];
    __shared__ __align__(16) float xT[32 * 68];
    const int t  = threadIdx.x;
    const int cg = t & 15;
    const int rg = t >> 4;
    const int row0 = blockIdx.x * 64;

    float acc[4][4] = {};
    for (int kk = 0; kk < 128; kk += 32) {
        for (int i = t; i < 32 * 64; i += 256) {
            int kl = i >> 6, c = i & 63;
            Wsh[i] = W[(kk + kl) * 64 + c];
        }
        for (int i = t; i < 64 * 32; i += 256) {
            int r = i >> 5, kl = i & 31;
            int row = row0 + r;
            xT[kl * 68 + r] = (row < N) ? h[(size_t)row * 128 + kk + kl] : 0.0f;
        }
        __syncthreads();
        #pragma unroll
        for (int kl = 0; kl < 32; ++kl) {
            float xv[4], wv[4];
            *(float4*)xv = *(const float4*)&xT[kl * 68 + rg * 4];
            *(float4*)wv = *(const float4*)&Wsh[kl * 64 + cg * 4];
            #pragma unroll
            for (int r = 0; r < 4; ++r)
                #pragma unroll
                for (int c = 0; c < 4; ++c)
                    acc[r][c] = fmaf(xv[r], wv[c], acc[r][c]);
        }
        __syncthreads();
    }

    float asv[4], adv[4];
    *(float4*)asv = *(const float4*)&att_src[cg * 4];
    *(float4*)adv = *(const float4*)&att_dst[cg * 4];

    #pragma unroll
    for (int r = 0; r < 4; ++r) {
        int row = row0 + rg * 4 + r;
        float s = acc[r][0]*asv[0] + acc[r][1]*asv[1] + acc[r][2]*asv[2] + acc[r][3]*asv[3];
        float d = acc[r][0]*adv[0] + acc[r][1]*adv[1] + acc[r][2]*adv[2] + acc[r][3]*adv[3];
        #pragma unroll
        for (int off = 1; off < 16; off <<= 1) {
            s += __shfl_xor(s, off, 16);
            d += __shfl_xor(d, off, 16);
        }
        if (row < N) {
            *(float4*)&h2[(size_t)row * 64 + cg * 4] =
                make_float4(acc[r][0], acc[r][1], acc[r][2], acc[r][3]);
            if (cg == 0) { as2[row] = s; ad2[row] = d; }
        }
    }
}

// ---------------- counting sort by dst ----------------
__global__ __launch_bounds__(256) void hist_kernel(const int* __restrict__ ei,
                                                   int* __restrict__ cnt, int E)
{
    int e = blockIdx.x * 256 + threadIdx.x;
    if (e < E) atomicAdd(&cnt[ei[E + e]], 1);
}

// scan A: per-1024-block sums
__global__ __launch_bounds__(256) void scanA_kernel(const int* __restrict__ cnt,
                                                    int* __restrict__ bsum, int N)
{
    __shared__ int red[256];
    int t = threadIdx.x;
    int i0 = blockIdx.x * 1024 + t * 4;
    int s = 0;
    if (i0 + 3 < N) {
        int4 v = *(const int4*)&cnt[i0];
        s = v.x + v.y + v.z + v.w;
    } else {
        for (int k = 0; k < 4; ++k) if (i0 + k < N) s += cnt[i0 + k];
    }
    red[t] = s; __syncthreads();
    for (int off = 128; off > 0; off >>= 1) {
        if (t < off) red[t] += red[t + off];
        __syncthreads();
    }
    if (t == 0) bsum[blockIdx.x] = red[0];
}

// scan B: exclusive scan of block sums (nb <= 256), single block
__global__ __launch_bounds__(256) void scanB_kernel(int* __restrict__ bsum, int nb)
{
    __shared__ int sc[256];
    int t = threadIdx.x;
    int v = (t < nb) ? bsum[t] : 0;
    sc[t] = v; __syncthreads();
    for (int off = 1; off < 256; off <<= 1) {
        int add = 0;
        if (t >= off) add = sc[t - off];
        __syncthreads();
        sc[t] += add;
        __syncthreads();
    }
    if (t < nb) bsum[t] = sc[t] - v;  // exclusive
}

// scan C: per-block exclusive scan + block offset -> row_start, cursor
__global__ __launch_bounds__(256) void scanC_kernel(const int* __restrict__ cnt,
                                                    const int* __restrict__ bsum,
                                                    int* __restrict__ row_start,
                                                    int* __restrict__ cursor, int N, int E)
{
    __shared__ int sc[256];
    int t = threadIdx.x;
    int i0 = blockIdx.x * 1024 + t * 4;
    int c0 = 0, c1 = 0, c2 = 0, c3 = 0;
    if (i0 + 3 < N) {
        int4 v = *(const int4*)&cnt[i0];
        c0 = v.x; c1 = v.y; c2 = v.z; c3 = v.w;
    } else {
        if (i0     < N) c0 = cnt[i0];
        if (i0 + 1 < N) c1 = cnt[i0 + 1];
        if (i0 + 2 < N) c2 = cnt[i0 + 2];
        if (i0 + 3 < N) c3 = cnt[i0 + 3];
    }
    int tot = c0 + c1 + c2 + c3;
    sc[t] = tot; __syncthreads();
    for (int off = 1; off < 256; off <<= 1) {
        int add = 0;
        if (t >= off) add = sc[t - off];
        __syncthreads();
        sc[t] += add;
        __syncthreads();
    }
    int ex = bsum[blockIdx.x] + sc[t] - tot;
    int e0 = ex, e1 = ex + c0, e2 = e1 + c1, e3 = e2 + c2;
    if (i0     < N) { row_start[i0]     = e0; cursor[i0]     = e0; }
    if (i0 + 1 < N) { row_start[i0 + 1] = e1; cursor[i0 + 1] = e1; }
    if (i0 + 2 < N) { row_start[i0 + 2] = e2; cursor[i0 + 2] = e2; }
    if (i0 + 3 < N) { row_start[i0 + 3] = e3; cursor[i0 + 3] = e3; }
    if (blockIdx.x == 0 && t == 0) row_start[N] = E;
}

__global__ __launch_bounds__(256) void fill_kernel(const int* __restrict__ ei,
                                                   int* __restrict__ cursor,
                                                   int* __restrict__ sorted_src, int E)
{
    int e = blockIdx.x * 256 + threadIdx.x;
    if (e >= E) return;
    int s = ei[e], d = ei[E + e];
    int pos = atomicAdd(&cursor[d], 1);
    sorted_src[pos] = s;
}

// ---------------- gather layer 1: out = elu(softmax-weighted sum + b1) ----------------
// 256 threads = 2 nodes x 128 channels
__global__ __launch_bounds__(256) void gather1_kernel(
    const int* __restrict__ row_start, const int* __restrict__ sorted_src,
    const float* __restrict__ as1, const float* __restrict__ ad1,
    const float* __restrict__ h1, const float* __restrict__ b1,
    float* __restrict__ hbuf, int N)
{
    int node = blockIdx.x * 2 + (threadIdx.x >> 7);
    if (node >= N) return;
    int ch = threadIdx.x & 127;
    int hh = ch >> 4;
    int r0 = row_start[node], r1 = row_start[node + 1];
    float ad = ad1[node * 8 + hh];
    float acc = 0.0f, den = 0.0f;
    for (int j = r0; j < r1; ++j) {
        int src = sorted_src[j];
        float ev = as1[src * 8 + hh] + ad;
        ev = ev > 0.0f ? ev : SLOPE * ev;
        float w = __expf(ev);
        den += w;
        acc = fmaf(w, h1[(size_t)src * 128 + ch], acc);
    }
    float v = acc / (den + EPSV) + b1[ch];
    hbuf[(size_t)node * 128 + ch] = v > 0.0f ? v : expm1f(v);
}

// ---------------- gather layer 2: out = b2 + softmax-weighted sum ----------------
// 256 threads = 4 nodes x 64 channels
__global__ __launch_bounds__(256) void gather2_kernel(
    const int* __restrict__ row_start, const int* __restrict__ sorted_src,
    const float* __restrict__ as2, const float* __restrict__ ad2,
    const float* __restrict__ h2, const float* __restrict__ b2,
    float* __restrict__ out, int N)
{
    int node = blockIdx.x * 4 + (threadIdx.x >> 6);
    if (node >= N) return;
    int ch = threadIdx.x & 63;
    int r0 = row_start[node], r1 = row_start[node + 1];
    float ad = ad2[node];
    float acc = 0.0f, den = 0.0f;
    for (int j = r0; j < r1; ++j) {
        int src = sorted_src[j];
        float ev = as2[src] + ad;
        ev = ev > 0.0f ? ev : SLOPE * ev;
        float w = __expf(ev);
        den += w;
        acc = fmaf(w, h2[(size_t)src * 64 + ch], acc);
    }
    out[(size_t)node * 64 + ch] = b2[ch] + acc / (den + EPSV);
}

extern "C" void kernel_launch(void* const* d_in, const int* in_sizes, int n_in,
                              void* d_out, int out_size, void* d_ws, size_t ws_size,
                              hipStream_t stream)
{
    const int N = in_sizes[0] / 128;
    const int E = in_sizes[1] / 2;

    const float* x        = (const float*)d_in[0];
    const int*   ei       = (const int*)  d_in[1];
    const float* W1       = (const float*)d_in[2];
    const float* att_src1 = (const float*)d_in[3];
    const float* att_dst1 = (const float*)d_in[4];
    const float* b1       = (const float*)d_in[5];
    const float* W2       = (const float*)d_in[6];
    const float* att_src2 = (const float*)d_in[7];
    const float* att_dst2 = (const float*)d_in[8];
    const float* b2       = (const float*)d_in[9];
    float* out = (float*)d_out;

    float* ws   = (float*)d_ws;
    float* h1   = ws;                         // N*128 (later reused as h2)
    float* hbuf = h1   + (size_t)N * 128;     // N*128
    float* as1  = hbuf + (size_t)N * 128;     // N*8
    float* ad1  = as1  + (size_t)N * 8;       // N*8
    float* as2  = ad1  + (size_t)N * 8;       // N
    float* ad2  = as2  + (size_t)N;           // N
    int* row_start  = (int*)(ad2 + N);        // N+1
    int* cursor     = row_start + (N + 1);    // N
    int* bsum       = cursor + N;             // 1024
    int* sorted_src = bsum + 1024;            // E
    float* h2 = h1;                           // alias: h1 dead after gather1

    const int nb = (N + 1023) / 1024;

    // --- counting sort by dst (overlaps nothing; independent of gemm1) ---
    hipMemsetAsync(cursor, 0, (size_t)N * sizeof(int), stream);
    hist_kernel <<<(E + 255) / 256, 256, 0, stream>>>(ei, cursor, E);
    scanA_kernel<<<nb, 256, 0, stream>>>(cursor, bsum, N);
    scanB_kernel<<<1, 256, 0, stream>>>(bsum, nb);
    scanC_kernel<<<nb, 256, 0, stream>>>(cursor, bsum, row_start, cursor, N, E);
    fill_kernel <<<(E + 255) / 256, 256, 0, stream>>>(ei, cursor, sorted_src, E);

    // --- layer 1 ---
    gemm1_kernel<<<(N + 31) / 32, 256, 0, stream>>>(x, W1, att_src1, att_dst1, h1, as1, ad1, N);
    gather1_kernel<<<(N + 1) / 2, 256, 0, stream>>>(row_start, sorted_src, as1, ad1, h1, b1, hbuf, N);

    // --- layer 2 ---
    gemm2_kernel<<<(N + 63) / 64, 256, 0, stream>>>(hbuf, W2, att_src2, att_dst2, h2, as2, ad2, N);
    gather2_kernel<<<(N + 3) / 4, 256, 0, stream>>>(row_start, sorted_src, as2, ad2, h2, b2, out, N);
}

// Round 3
// 608.065 us; speedup vs baseline: 3.1392x; 1.2966x over previous
//
#include <hip/hip_runtime.h>
#include <hip/hip_bf16.h>

#define SLOPE 0.2f
#define EPSV 1e-16f
#define H1S 136   // 128 channels + 8 a_src values (16B-aligned rows)
#define H2S 68    // 64 channels + 1 a_src value + 3 pad

// ---------------- GEMM1: h1p = x @ W1 (stride 136, a_src packed at +128) ----------------
__global__ __launch_bounds__(256) void gemm1_kernel(
    const float* __restrict__ x, const float* __restrict__ W,
    const float* __restrict__ att_src, const float* __restrict__ att_dst,
    float* __restrict__ h1p, float* __restrict__ ad1, int N)
{
    __shared__ __align__(16) float Wsh[32 * 128];
    __shared__ __align__(16) float xT[32 * 36];
    const int t  = threadIdx.x;
    const int cg = t & 31;
    const int rg = t >> 5;
    const int row0 = blockIdx.x * 32;

    float acc[4][4] = {};
    for (int kk = 0; kk < 128; kk += 32) {
        for (int i = t; i < 32 * 128; i += 256) {
            int kl = i >> 7, c = i & 127;
            Wsh[i] = W[(kk + kl) * 128 + c];
        }
        for (int i = t; i < 32 * 32; i += 256) {
            int r = i >> 5, kl = i & 31;
            int row = row0 + r;
            xT[kl * 36 + r] = (row < N) ? x[(size_t)row * 128 + kk + kl] : 0.0f;
        }
        __syncthreads();
        #pragma unroll
        for (int kl = 0; kl < 32; ++kl) {
            float xv[4], wv[4];
            *(float4*)xv = *(const float4*)&xT[kl * 36 + rg * 4];
            *(float4*)wv = *(const float4*)&Wsh[kl * 128 + cg * 4];
            #pragma unroll
            for (int r = 0; r < 4; ++r)
                #pragma unroll
                for (int c = 0; c < 4; ++c)
                    acc[r][c] = fmaf(xv[r], wv[c], acc[r][c]);
        }
        __syncthreads();
    }

    float asv[4], adv[4];
    *(float4*)asv = *(const float4*)&att_src[cg * 4];
    *(float4*)adv = *(const float4*)&att_dst[cg * 4];
    const int head = cg >> 2;

    #pragma unroll
    for (int r = 0; r < 4; ++r) {
        int row = row0 + rg * 4 + r;
        float s = acc[r][0]*asv[0] + acc[r][1]*asv[1] + acc[r][2]*asv[2] + acc[r][3]*asv[3];
        float d = acc[r][0]*adv[0] + acc[r][1]*adv[1] + acc[r][2]*adv[2] + acc[r][3]*adv[3];
        s += __shfl_xor(s, 1, 4); s += __shfl_xor(s, 2, 4);
        d += __shfl_xor(d, 1, 4); d += __shfl_xor(d, 2, 4);
        if (row < N) {
            *(float4*)&h1p[(size_t)row * H1S + cg * 4] =
                make_float4(acc[r][0], acc[r][1], acc[r][2], acc[r][3]);
            if ((cg & 3) == 0) {
                h1p[(size_t)row * H1S + 128 + head] = s;
                ad1[row * 8 + head] = d;
            }
        }
    }
}

// ---------------- GEMM2: h2p = h @ W2 (stride 68, a_src packed at +64) ----------------
__global__ __launch_bounds__(256) void gemm2_kernel(
    const float* __restrict__ h, const float* __restrict__ W,
    const float* __restrict__ att_src, const float* __restrict__ att_dst,
    float* __restrict__ h2p, float* __restrict__ ad2, int N)
{
    __shared__ __align__(16) float Wsh[32 * 64];
    __shared__ __align__(16) float xT[32 * 68];
    const int t  = threadIdx.x;
    const int cg = t & 15;
    const int rg = t >> 4;
    const int row0 = blockIdx.x * 64;

    float acc[4][4] = {};
    for (int kk = 0; kk < 128; kk += 32) {
        for (int i = t; i < 32 * 64; i += 256) {
            int kl = i >> 6, c = i & 63;
            Wsh[i] = W[(kk + kl) * 64 + c];
        }
        for (int i = t; i < 64 * 32; i += 256) {
            int r = i >> 5, kl = i & 31;
            int row = row0 + r;
            xT[kl * 68 + r] = (row < N) ? h[(size_t)row * 128 + kk + kl] : 0.0f;
        }
        __syncthreads();
        #pragma unroll
        for (int kl = 0; kl < 32; ++kl) {
            float xv[4], wv[4];
            *(float4*)xv = *(const float4*)&xT[kl * 68 + rg * 4];
            *(float4*)wv = *(const float4*)&Wsh[kl * 64 + cg * 4];
            #pragma unroll
            for (int r = 0; r < 4; ++r)
                #pragma unroll
                for (int c = 0; c < 4; ++c)
                    acc[r][c] = fmaf(xv[r], wv[c], acc[r][c]);
        }
        __syncthreads();
    }

    float asv[4], adv[4];
    *(float4*)asv = *(const float4*)&att_src[cg * 4];
    *(float4*)adv = *(const float4*)&att_dst[cg * 4];

    #pragma unroll
    for (int r = 0; r < 4; ++r) {
        int row = row0 + rg * 4 + r;
        float s = acc[r][0]*asv[0] + acc[r][1]*asv[1] + acc[r][2]*asv[2] + acc[r][3]*asv[3];
        float d = acc[r][0]*adv[0] + acc[r][1]*adv[1] + acc[r][2]*adv[2] + acc[r][3]*adv[3];
        #pragma unroll
        for (int off = 1; off < 16; off <<= 1) {
            s += __shfl_xor(s, off, 16);
            d += __shfl_xor(d, off, 16);
        }
        if (row < N) {
            *(float4*)&h2p[(size_t)row * H2S + cg * 4] =
                make_float4(acc[r][0], acc[r][1], acc[r][2], acc[r][3]);
            if (cg == 0) { h2p[(size_t)row * H2S + 64] = s; ad2[row] = d; }
        }
    }
}

// ---------------- counting sort by dst ----------------
__global__ __launch_bounds__(256) void hist_kernel(const int* __restrict__ ei,
                                                   int* __restrict__ cnt, int E)
{
    int e = blockIdx.x * 256 + threadIdx.x;
    if (e < E) atomicAdd(&cnt[ei[E + e]], 1);
}

__global__ __launch_bounds__(256) void scanA_kernel(const int* __restrict__ cnt,
                                                    int* __restrict__ bsum, int N)
{
    __shared__ int red[256];
    int t = threadIdx.x;
    int i0 = blockIdx.x * 1024 + t * 4;
    int s = 0;
    if (i0 + 3 < N) {
        int4 v = *(const int4*)&cnt[i0];
        s = v.x + v.y + v.z + v.w;
    } else {
        for (int k = 0; k < 4; ++k) if (i0 + k < N) s += cnt[i0 + k];
    }
    red[t] = s; __syncthreads();
    for (int off = 128; off > 0; off >>= 1) {
        if (t < off) red[t] += red[t + off];
        __syncthreads();
    }
    if (t == 0) bsum[blockIdx.x] = red[0];
}

__global__ __launch_bounds__(256) void scanB_kernel(int* __restrict__ bsum, int nb)
{
    __shared__ int sc[256];
    int t = threadIdx.x;
    int v = (t < nb) ? bsum[t] : 0;
    sc[t] = v; __syncthreads();
    for (int off = 1; off < 256; off <<= 1) {
        int add = 0;
        if (t >= off) add = sc[t - off];
        __syncthreads();
        sc[t] += add;
        __syncthreads();
    }
    if (t < nb) bsum[t] = sc[t] - v;  // exclusive
}

__global__ __launch_bounds__(256) void scanC_kernel(const int* __restrict__ cnt,
                                                    const int* __restrict__ bsum,
                                                    int* __restrict__ row_start,
                                                    int* __restrict__ cursor, int N, int E)
{
    __shared__ int sc[256];
    int t = threadIdx.x;
    int i0 = blockIdx.x * 1024 + t * 4;
    int c0 = 0, c1 = 0, c2 = 0, c3 = 0;
    if (i0 + 3 < N) {
        int4 v = *(const int4*)&cnt[i0];
        c0 = v.x; c1 = v.y; c2 = v.z; c3 = v.w;
    } else {
        if (i0     < N) c0 = cnt[i0];
        if (i0 + 1 < N) c1 = cnt[i0 + 1];
        if (i0 + 2 < N) c2 = cnt[i0 + 2];
        if (i0 + 3 < N) c3 = cnt[i0 + 3];
    }
    int tot = c0 + c1 + c2 + c3;
    sc[t] = tot; __syncthreads();
    for (int off = 1; off < 256; off <<= 1) {
        int add = 0;
        if (t >= off) add = sc[t - off];
        __syncthreads();
        sc[t] += add;
        __syncthreads();
    }
    int ex = bsum[blockIdx.x] + sc[t] - tot;
    int e0 = ex, e1 = ex + c0, e2 = e1 + c1, e3 = e2 + c2;
    if (i0     < N) { row_start[i0]     = e0; cursor[i0]     = e0; }
    if (i0 + 1 < N) { row_start[i0 + 1] = e1; cursor[i0 + 1] = e1; }
    if (i0 + 2 < N) { row_start[i0 + 2] = e2; cursor[i0 + 2] = e2; }
    if (i0 + 3 < N) { row_start[i0 + 3] = e3; cursor[i0 + 3] = e3; }
    if (blockIdx.x == 0 && t == 0) row_start[N] = E;
}

__global__ __launch_bounds__(256) void fill_kernel(const int* __restrict__ ei,
                                                   int* __restrict__ cursor,
                                                   int* __restrict__ sorted_src, int E)
{
    int e = blockIdx.x * 256 + threadIdx.x;
    if (e >= E) return;
    int s = ei[e], d = ei[E + e];
    int pos = atomicAdd(&cursor[d], 1);
    sorted_src[pos] = s;
}

// ---------------- gather layer 1: hbuf = elu(softmax-weighted sum + b1) ----------------
// 256 threads = 2 nodes x 128 channels; edge loop 4-wide with masked tail
__global__ __launch_bounds__(256) void gather1_kernel(
    const int* __restrict__ row_start, const int* __restrict__ sorted_src,
    const float* __restrict__ ad1, const float* __restrict__ h1p,
    const float* __restrict__ b1, float* __restrict__ hbuf, int N)
{
    int node = blockIdx.x * 2 + (threadIdx.x >> 7);
    if (node >= N) return;
    int ch = threadIdx.x & 127;
    int hh = ch >> 4;
    int r0 = row_start[node], r1 = row_start[node + 1];
    float ad = ad1[node * 8 + hh];
    float acc = 0.0f, den = 0.0f;
    for (int j = r0; j < r1; j += 4) {
        int   srcs[4];
        bool  valid[4];
        #pragma unroll
        for (int k = 0; k < 4; ++k) {
            int jj = j + k;
            valid[k] = jj < r1;
            srcs[k] = sorted_src[valid[k] ? jj : r0];
        }
        float av[4], hv[4];
        #pragma unroll
        for (int k = 0; k < 4; ++k) {
            size_t base = (size_t)srcs[k] * H1S;
            av[k] = h1p[base + 128 + hh];
            hv[k] = h1p[base + ch];
        }
        #pragma unroll
        for (int k = 0; k < 4; ++k) {
            float ev = av[k] + ad;
            ev = ev > 0.0f ? ev : SLOPE * ev;
            float w = valid[k] ? __expf(ev) : 0.0f;
            den += w;
            acc = fmaf(w, hv[k], acc);
        }
    }
    float v = acc / (den + EPSV) + b1[ch];
    hbuf[(size_t)node * 128 + ch] = v > 0.0f ? v : expm1f(v);
}

// ---------------- gather layer 2: out = b2 + softmax-weighted sum ----------------
// 256 threads = 4 nodes x 64 channels; edge loop 4-wide with masked tail
__global__ __launch_bounds__(256) void gather2_kernel(
    const int* __restrict__ row_start, const int* __restrict__ sorted_src,
    const float* __restrict__ ad2, const float* __restrict__ h2p,
    const float* __restrict__ b2, float* __restrict__ out, int N)
{
    int node = blockIdx.x * 4 + (threadIdx.x >> 6);
    if (node >= N) return;
    int ch = threadIdx.x & 63;
    int r0 = row_start[node], r1 = row_start[node + 1];
    float ad = ad2[node];
    float acc = 0.0f, den = 0.0f;
    for (int j = r0; j < r1; j += 4) {
        int   srcs[4];
        bool  valid[4];
        #pragma unroll
        for (int k = 0; k < 4; ++k) {
            int jj = j + k;
            valid[k] = jj < r1;
            srcs[k] = sorted_src[valid[k] ? jj : r0];
        }
        float av[4], hv[4];
        #pragma unroll
        for (int k = 0; k < 4; ++k) {
            size_t base = (size_t)srcs[k] * H2S;
            av[k] = h2p[base + 64];
            hv[k] = h2p[base + ch];
        }
        #pragma unroll
        for (int k = 0; k < 4; ++k) {
            float ev = av[k] + ad;
            ev = ev > 0.0f ? ev : SLOPE * ev;
            float w = valid[k] ? __expf(ev) : 0.0f;
            den += w;
            acc = fmaf(w, hv[k], acc);
        }
    }
    out[(size_t)node * 64 + ch] = b2[ch] + acc / (den + EPSV);
}

extern "C" void kernel_launch(void* const* d_in, const int* in_sizes, int n_in,
                              void* d_out, int out_size, void* d_ws, size_t ws_size,
                              hipStream_t stream)
{
    const int N = in_sizes[0] / 128;
    const int E = in_sizes[1] / 2;

    const float* x        = (const float*)d_in[0];
    const int*   ei       = (const int*)  d_in[1];
    const float* W1       = (const float*)d_in[2];
    const float* att_src1 = (const float*)d_in[3];
    const float* att_dst1 = (const float*)d_in[4];
    const float* b1       = (const float*)d_in[5];
    const float* W2       = (const float*)d_in[6];
    const float* att_src2 = (const float*)d_in[7];
    const float* att_dst2 = (const float*)d_in[8];
    const float* b2       = (const float*)d_in[9];
    float* out = (float*)d_out;

    float* ws   = (float*)d_ws;
    float* h1p  = ws;                          // N*136 (later reused as h2p, N*68)
    float* hbuf = h1p  + (size_t)N * H1S;      // N*128
    float* ad1  = hbuf + (size_t)N * 128;      // N*8
    float* ad2  = ad1  + (size_t)N * 8;        // N
    int* row_start  = (int*)(ad2 + N);         // N+1
    int* cursor     = row_start + (N + 1);     // N
    int* bsum       = cursor + N;              // 1024
    int* sorted_src = bsum + 1024;             // E (+ slack)
    float* h2p = h1p;                          // alias: h1p dead after gather1

    const int nb = (N + 1023) / 1024;

    // --- counting sort by dst ---
    hipMemsetAsync(cursor, 0, (size_t)N * sizeof(int), stream);
    hist_kernel <<<(E + 255) / 256, 256, 0, stream>>>(ei, cursor, E);
    scanA_kernel<<<nb, 256, 0, stream>>>(cursor, bsum, N);
    scanB_kernel<<<1, 256, 0, stream>>>(bsum, nb);
    scanC_kernel<<<nb, 256, 0, stream>>>(cursor, bsum, row_start, cursor, N, E);
    fill_kernel <<<(E + 255) / 256, 256, 0, stream>>>(ei, cursor, sorted_src, E);

    // --- layer 1 ---
    gemm1_kernel<<<(N + 31) / 32, 256, 0, stream>>>(x, W1, att_src1, att_dst1, h1p, ad1, N);
    gather1_kernel<<<(N + 1) / 2, 256, 0, stream>>>(row_start, sorted_src, ad1, h1p, b1, hbuf, N);

    // --- layer 2 ---
    gemm2_kernel<<<(N + 63) / 64, 256, 0, stream>>>(hbuf, W2, att_src2, att_dst2, h2p, ad2, N);
    gather2_kernel<<<(N + 3) / 4, 256, 0, stream>>>(row_start, sorted_src, ad2, h2p, b2, out, N);
}

// Round 4
// 475.026 us; speedup vs baseline: 4.0184x; 1.2801x over previous
//
#include <hip/hip_runtime.h>
#include <hip/hip_bf16.h>
#include <stdint.h>

#define SLOPE 0.2f
#define EPSV 1e-16f
#define H1W 72    // row stride in u32 words: 64 bf16x2 words + 8 fp32 a_src
#define H2W 36    // 32 bf16x2 words + 1 fp32 a_src + 3 pad

static __device__ __forceinline__ uint32_t pack_bf16x2(float a, float b) {
    uint32_t ua = __float_as_uint(a), ub = __float_as_uint(b);
    ua = (ua + 0x7fffu + ((ua >> 16) & 1u)) >> 16;   // RTNE
    ub = (ub + 0x7fffu + ((ub >> 16) & 1u)) >> 16;
    return ua | (ub << 16);
}

// ---------------- GEMM1: h1p(bf16,stride 72w) = x @ W1, a_src packed at word 64 ----------------
__global__ __launch_bounds__(256) void gemm1_kernel(
    const float* __restrict__ x, const float* __restrict__ W,
    const float* __restrict__ att_src, const float* __restrict__ att_dst,
    uint32_t* __restrict__ h1p, float* __restrict__ ad1, int N)
{
    __shared__ __align__(16) float Wsh[32 * 128];
    __shared__ __align__(16) float xT[32 * 36];
    const int t  = threadIdx.x;
    const int cg = t & 31;
    const int rg = t >> 5;
    const int row0 = blockIdx.x * 32;

    float acc[4][4] = {};
    for (int kk = 0; kk < 128; kk += 32) {
        for (int i = t; i < 32 * 128; i += 256) {
            int kl = i >> 7, c = i & 127;
            Wsh[i] = W[(kk + kl) * 128 + c];
        }
        for (int i = t; i < 32 * 32; i += 256) {
            int r = i >> 5, kl = i & 31;
            int row = row0 + r;
            xT[kl * 36 + r] = (row < N) ? x[(size_t)row * 128 + kk + kl] : 0.0f;
        }
        __syncthreads();
        #pragma unroll
        for (int kl = 0; kl < 32; ++kl) {
            float xv[4], wv[4];
            *(float4*)xv = *(const float4*)&xT[kl * 36 + rg * 4];
            *(float4*)wv = *(const float4*)&Wsh[kl * 128 + cg * 4];
            #pragma unroll
            for (int r = 0; r < 4; ++r)
                #pragma unroll
                for (int c = 0; c < 4; ++c)
                    acc[r][c] = fmaf(xv[r], wv[c], acc[r][c]);
        }
        __syncthreads();
    }

    float asv[4], adv[4];
    *(float4*)asv = *(const float4*)&att_src[cg * 4];
    *(float4*)adv = *(const float4*)&att_dst[cg * 4];
    const int head = cg >> 2;

    #pragma unroll
    for (int r = 0; r < 4; ++r) {
        int row = row0 + rg * 4 + r;
        float s = acc[r][0]*asv[0] + acc[r][1]*asv[1] + acc[r][2]*asv[2] + acc[r][3]*asv[3];
        float d = acc[r][0]*adv[0] + acc[r][1]*adv[1] + acc[r][2]*adv[2] + acc[r][3]*adv[3];
        s += __shfl_xor(s, 1, 4); s += __shfl_xor(s, 2, 4);
        d += __shfl_xor(d, 1, 4); d += __shfl_xor(d, 2, 4);
        if (row < N) {
            uint2 pw = make_uint2(pack_bf16x2(acc[r][0], acc[r][1]),
                                  pack_bf16x2(acc[r][2], acc[r][3]));
            *(uint2*)&h1p[(size_t)row * H1W + cg * 2] = pw;
            if ((cg & 3) == 0) {
                h1p[(size_t)row * H1W + 64 + head] = __float_as_uint(s);
                ad1[row * 8 + head] = d;
            }
        }
    }
}

// ---------------- GEMM2: h2p(bf16,stride 36w) = h @ W2, a_src packed at word 32 ----------------
__global__ __launch_bounds__(256) void gemm2_kernel(
    const float* __restrict__ h, const float* __restrict__ W,
    const float* __restrict__ att_src, const float* __restrict__ att_dst,
    uint32_t* __restrict__ h2p, float* __restrict__ ad2, int N)
{
    __shared__ __align__(16) float Wsh[32 * 64];
    __shared__ __align__(16) float xT[32 * 68];
    const int t  = threadIdx.x;
    const int cg = t & 15;
    const int rg = t >> 4;
    const int row0 = blockIdx.x * 64;

    float acc[4][4] = {};
    for (int kk = 0; kk < 128; kk += 32) {
        for (int i = t; i < 32 * 64; i += 256) {
            int kl = i >> 6, c = i & 63;
            Wsh[i] = W[(kk + kl) * 64 + c];
        }
        for (int i = t; i < 64 * 32; i += 256) {
            int r = i >> 5, kl = i & 31;
            int row = row0 + r;
            xT[kl * 68 + r] = (row < N) ? h[(size_t)row * 128 + kk + kl] : 0.0f;
        }
        __syncthreads();
        #pragma unroll
        for (int kl = 0; kl < 32; ++kl) {
            float xv[4], wv[4];
            *(float4*)xv = *(const float4*)&xT[kl * 68 + rg * 4];
            *(float4*)wv = *(const float4*)&Wsh[kl * 64 + cg * 4];
            #pragma unroll
            for (int r = 0; r < 4; ++r)
                #pragma unroll
                for (int c = 0; c < 4; ++c)
                    acc[r][c] = fmaf(xv[r], wv[c], acc[r][c]);
        }
        __syncthreads();
    }

    float asv[4], adv[4];
    *(float4*)asv = *(const float4*)&att_src[cg * 4];
    *(float4*)adv = *(const float4*)&att_dst[cg * 4];

    #pragma unroll
    for (int r = 0; r < 4; ++r) {
        int row = row0 + rg * 4 + r;
        float s = acc[r][0]*asv[0] + acc[r][1]*asv[1] + acc[r][2]*asv[2] + acc[r][3]*asv[3];
        float d = acc[r][0]*adv[0] + acc[r][1]*adv[1] + acc[r][2]*adv[2] + acc[r][3]*adv[3];
        #pragma unroll
        for (int off = 1; off < 16; off <<= 1) {
            s += __shfl_xor(s, off, 16);
            d += __shfl_xor(d, off, 16);
        }
        if (row < N) {
            uint2 pw = make_uint2(pack_bf16x2(acc[r][0], acc[r][1]),
                                  pack_bf16x2(acc[r][2], acc[r][3]));
            *(uint2*)&h2p[(size_t)row * H2W + cg * 2] = pw;
            if (cg == 0) { h2p[(size_t)row * H2W + 32] = __float_as_uint(s); ad2[row] = d; }
        }
    }
}

// ---------------- counting sort by dst ----------------
__global__ __launch_bounds__(256) void hist_kernel(const int* __restrict__ ei,
                                                   int* __restrict__ cnt, int E)
{
    int e = blockIdx.x * 256 + threadIdx.x;
    if (e < E) atomicAdd(&cnt[ei[E + e]], 1);
}

__global__ __launch_bounds__(256) void scanA_kernel(const int* __restrict__ cnt,
                                                    int* __restrict__ bsum, int N)
{
    __shared__ int red[256];
    int t = threadIdx.x;
    int i0 = blockIdx.x * 1024 + t * 4;
    int s = 0;
    if (i0 + 3 < N) {
        int4 v = *(const int4*)&cnt[i0];
        s = v.x + v.y + v.z + v.w;
    } else {
        for (int k = 0; k < 4; ++k) if (i0 + k < N) s += cnt[i0 + k];
    }
    red[t] = s; __syncthreads();
    for (int off = 128; off > 0; off >>= 1) {
        if (t < off) red[t] += red[t + off];
        __syncthreads();
    }
    if (t == 0) bsum[blockIdx.x] = red[0];
}

__global__ __launch_bounds__(256) void scanB_kernel(int* __restrict__ bsum, int nb)
{
    __shared__ int sc[256];
    int t = threadIdx.x;
    int v = (t < nb) ? bsum[t] : 0;
    sc[t] = v; __syncthreads();
    for (int off = 1; off < 256; off <<= 1) {
        int add = 0;
        if (t >= off) add = sc[t - off];
        __syncthreads();
        sc[t] += add;
        __syncthreads();
    }
    if (t < nb) bsum[t] = sc[t] - v;  // exclusive
}

__global__ __launch_bounds__(256) void scanC_kernel(const int* __restrict__ cnt,
                                                    const int* __restrict__ bsum,
                                                    int* __restrict__ row_start,
                                                    int* __restrict__ cursor, int N, int E)
{
    __shared__ int sc[256];
    int t = threadIdx.x;
    int i0 = blockIdx.x * 1024 + t * 4;
    int c0 = 0, c1 = 0, c2 = 0, c3 = 0;
    if (i0 + 3 < N) {
        int4 v = *(const int4*)&cnt[i0];
        c0 = v.x; c1 = v.y; c2 = v.z; c3 = v.w;
    } else {
        if (i0     < N) c0 = cnt[i0];
        if (i0 + 1 < N) c1 = cnt[i0 + 1];
        if (i0 + 2 < N) c2 = cnt[i0 + 2];
        if (i0 + 3 < N) c3 = cnt[i0 + 3];
    }
    int tot = c0 + c1 + c2 + c3;
    sc[t] = tot; __syncthreads();
    for (int off = 1; off < 256; off <<= 1) {
        int add = 0;
        if (t >= off) add = sc[t - off];
        __syncthreads();
        sc[t] += add;
        __syncthreads();
    }
    int ex = bsum[blockIdx.x] + sc[t] - tot;
    int e0 = ex, e1 = ex + c0, e2 = e1 + c1, e3 = e2 + c2;
    if (i0     < N) { row_start[i0]     = e0; cursor[i0]     = e0; }
    if (i0 + 1 < N) { row_start[i0 + 1] = e1; cursor[i0 + 1] = e1; }
    if (i0 + 2 < N) { row_start[i0 + 2] = e2; cursor[i0 + 2] = e2; }
    if (i0 + 3 < N) { row_start[i0 + 3] = e3; cursor[i0 + 3] = e3; }
    if (blockIdx.x == 0 && t == 0) row_start[N] = E;
}

__global__ __launch_bounds__(256) void fill_kernel(const int* __restrict__ ei,
                                                   int* __restrict__ cursor,
                                                   int* __restrict__ sorted_src, int E)
{
    int e = blockIdx.x * 256 + threadIdx.x;
    if (e >= E) return;
    int s = ei[e], d = ei[E + e];
    int pos = atomicAdd(&cursor[d], 1);
    sorted_src[pos] = s;
}

// ---------------- gather layer 1 (bf16): hbuf = elu(softmax-weighted sum + b1) ----------------
// 256 threads = 4 nodes x 64 threads; each thread = 2 channels (one bf16x2 word)
__global__ __launch_bounds__(256) void gather1_kernel(
    const int* __restrict__ row_start, const int* __restrict__ sorted_src,
    const float* __restrict__ ad1, const uint32_t* __restrict__ h1p,
    const float* __restrict__ b1, float* __restrict__ hbuf, int N)
{
    int node = blockIdx.x * 4 + (threadIdx.x >> 6);
    if (node >= N) return;
    int cw = threadIdx.x & 63;        // channel-word: channels 2cw, 2cw+1
    int hh = cw >> 3;                 // 8 words per head
    int r0 = row_start[node], r1 = row_start[node + 1];
    float ad = ad1[node * 8 + hh];
    float acc0 = 0.0f, acc1 = 0.0f, den = 0.0f;
    for (int j = r0; j < r1; j += 4) {
        int  srcs[4];
        bool valid[4];
        #pragma unroll
        for (int k = 0; k < 4; ++k) {
            int jj = j + k;
            valid[k] = jj < r1;
            srcs[k] = sorted_src[valid[k] ? jj : r0];
        }
        float    av[4];
        uint32_t hv[4];
        #pragma unroll
        for (int k = 0; k < 4; ++k) {
            size_t base = (size_t)srcs[k] * H1W;
            av[k] = __uint_as_float(h1p[base + 64 + hh]);
            hv[k] = h1p[base + cw];
        }
        #pragma unroll
        for (int k = 0; k < 4; ++k) {
            float ev = av[k] + ad;
            ev = ev > 0.0f ? ev : SLOPE * ev;
            float w = valid[k] ? __expf(ev) : 0.0f;
            den += w;
            float lo = __uint_as_float(hv[k] << 16);
            float hi = __uint_as_float(hv[k] & 0xffff0000u);
            acc0 = fmaf(w, lo, acc0);
            acc1 = fmaf(w, hi, acc1);
        }
    }
    float inv = 1.0f / (den + EPSV);
    float v0 = acc0 * inv + b1[cw * 2];
    float v1 = acc1 * inv + b1[cw * 2 + 1];
    v0 = v0 > 0.0f ? v0 : expm1f(v0);
    v1 = v1 > 0.0f ? v1 : expm1f(v1);
    *(float2*)&hbuf[(size_t)node * 128 + cw * 2] = make_float2(v0, v1);
}

// ---------------- gather layer 2 (bf16): out = b2 + softmax-weighted sum ----------------
// 256 threads = 8 nodes x 32 threads; each thread = 2 channels
__global__ __launch_bounds__(256) void gather2_kernel(
    const int* __restrict__ row_start, const int* __restrict__ sorted_src,
    const float* __restrict__ ad2, const uint32_t* __restrict__ h2p,
    const float* __restrict__ b2, float* __restrict__ out, int N)
{
    int node = blockIdx.x * 8 + (threadIdx.x >> 5);
    if (node >= N) return;
    int cw = threadIdx.x & 31;        // channels 2cw, 2cw+1
    int r0 = row_start[node], r1 = row_start[node + 1];
    float ad = ad2[node];
    float acc0 = 0.0f, acc1 = 0.0f, den = 0.0f;
    for (int j = r0; j < r1; j += 4) {
        int  srcs[4];
        bool valid[4];
        #pragma unroll
        for (int k = 0; k < 4; ++k) {
            int jj = j + k;
            valid[k] = jj < r1;
            srcs[k] = sorted_src[valid[k] ? jj : r0];
        }
        float    av[4];
        uint32_t hv[4];
        #pragma unroll
        for (int k = 0; k < 4; ++k) {
            size_t base = (size_t)srcs[k] * H2W;
            av[k] = __uint_as_float(h2p[base + 32]);
            hv[k] = h2p[base + cw];
        }
        #pragma unroll
        for (int k = 0; k < 4; ++k) {
            float ev = av[k] + ad;
            ev = ev > 0.0f ? ev : SLOPE * ev;
            float w = valid[k] ? __expf(ev) : 0.0f;
            den += w;
            float lo = __uint_as_float(hv[k] << 16);
            float hi = __uint_as_float(hv[k] & 0xffff0000u);
            acc0 = fmaf(w, lo, acc0);
            acc1 = fmaf(w, hi, acc1);
        }
    }
    float inv = 1.0f / (den + EPSV);
    *(float2*)&out[(size_t)node * 64 + cw * 2] =
        make_float2(acc0 * inv + b2[cw * 2], acc1 * inv + b2[cw * 2 + 1]);
}

extern "C" void kernel_launch(void* const* d_in, const int* in_sizes, int n_in,
                              void* d_out, int out_size, void* d_ws, size_t ws_size,
                              hipStream_t stream)
{
    const int N = in_sizes[0] / 128;
    const int E = in_sizes[1] / 2;

    const float* x        = (const float*)d_in[0];
    const int*   ei       = (const int*)  d_in[1];
    const float* W1       = (const float*)d_in[2];
    const float* att_src1 = (const float*)d_in[3];
    const float* att_dst1 = (const float*)d_in[4];
    const float* b1       = (const float*)d_in[5];
    const float* W2       = (const float*)d_in[6];
    const float* att_src2 = (const float*)d_in[7];
    const float* att_dst2 = (const float*)d_in[8];
    const float* b2       = (const float*)d_in[9];
    float* out = (float*)d_out;

    uint32_t* h1p  = (uint32_t*)d_ws;                 // N*72 words (reused as h2p N*36)
    float* hbuf    = (float*)(h1p + (size_t)N * H1W); // N*128
    float* ad1     = hbuf + (size_t)N * 128;          // N*8
    float* ad2     = ad1  + (size_t)N * 8;            // N
    int* row_start  = (int*)(ad2 + N);                // N+1
    int* cursor     = row_start + (N + 1);            // N
    int* bsum       = cursor + N;                     // 1024
    int* sorted_src = bsum + 1024;                    // E
    uint32_t* h2p   = h1p;                            // alias: h1p dead after gather1

    const int nb = (N + 1023) / 1024;

    // --- counting sort by dst ---
    hipMemsetAsync(cursor, 0, (size_t)N * sizeof(int), stream);
    hist_kernel <<<(E + 255) / 256, 256, 0, stream>>>(ei, cursor, E);
    scanA_kernel<<<nb, 256, 0, stream>>>(cursor, bsum, N);
    scanB_kernel<<<1, 256, 0, stream>>>(bsum, nb);
    scanC_kernel<<<nb, 256, 0, stream>>>(cursor, bsum, row_start, cursor, N, E);
    fill_kernel <<<(E + 255) / 256, 256, 0, stream>>>(ei, cursor, sorted_src, E);

    // --- layer 1 ---
    gemm1_kernel<<<(N + 31) / 32, 256, 0, stream>>>(x, W1, att_src1, att_dst1, h1p, ad1, N);
    gather1_kernel<<<(N + 3) / 4, 256, 0, stream>>>(row_start, sorted_src, ad1, h1p, b1, hbuf, N);

    // --- layer 2 ---
    gemm2_kernel<<<(N + 63) / 64, 256, 0, stream>>>(hbuf, W2, att_src2, att_dst2, h2p, ad2, N);
    gather2_kernel<<<(N + 7) / 8, 256, 0, stream>>>(row_start, sorted_src, ad2, h2p, b2, out, N);
}

// Round 5
// 341.270 us; speedup vs baseline: 5.5933x; 1.3919x over previous
//
#include <hip/hip_runtime.h>
#include <hip/hip_bf16.h>
#include <stdint.h>

#define SLOPE 0.2f
#define EPSV 1e-16f
#define H1W 72    // row stride in u32 words: 64 bf16x2 words + 8 fp32 a_src
#define H2W 36    // 32 bf16x2 words + 1 fp32 a_src + 3 pad

#define NPB   512   // nodes per bucket (pow2); bucket = dst >> 9
#define NBMAX 256   // max buckets (N <= 131072)
#define NBLK1 256   // pass-1 blocks

static __device__ __forceinline__ uint32_t pack_bf16x2(float a, float b) {
    uint32_t ua = __float_as_uint(a), ub = __float_as_uint(b);
    ua = (ua + 0x7fffu + ((ua >> 16) & 1u)) >> 16;   // RTNE
    ub = (ub + 0x7fffu + ((ub >> 16) & 1u)) >> 16;
    return ua | (ub << 16);
}

// ---------------- GEMM1: h1p(bf16,stride 72w) = x @ W1, a_src packed at word 64 ----------------
__global__ __launch_bounds__(256) void gemm1_kernel(
    const float* __restrict__ x, const float* __restrict__ W,
    const float* __restrict__ att_src, const float* __restrict__ att_dst,
    uint32_t* __restrict__ h1p, float* __restrict__ ad1, int N)
{
    __shared__ __align__(16) float Wsh[32 * 128];
    __shared__ __align__(16) float xT[32 * 36];
    const int t  = threadIdx.x;
    const int cg = t & 31;
    const int rg = t >> 5;
    const int row0 = blockIdx.x * 32;

    float acc[4][4] = {};
    for (int kk = 0; kk < 128; kk += 32) {
        for (int i = t; i < 32 * 128; i += 256) {
            int kl = i >> 7, c = i & 127;
            Wsh[i] = W[(kk + kl) * 128 + c];
        }
        for (int i = t; i < 32 * 32; i += 256) {
            int r = i >> 5, kl = i & 31;
            int row = row0 + r;
            xT[kl * 36 + r] = (row < N) ? x[(size_t)row * 128 + kk + kl] : 0.0f;
        }
        __syncthreads();
        #pragma unroll
        for (int kl = 0; kl < 32; ++kl) {
            float xv[4], wv[4];
            *(float4*)xv = *(const float4*)&xT[kl * 36 + rg * 4];
            *(float4*)wv = *(const float4*)&Wsh[kl * 128 + cg * 4];
            #pragma unroll
            for (int r = 0; r < 4; ++r)
                #pragma unroll
                for (int c = 0; c < 4; ++c)
                    acc[r][c] = fmaf(xv[r], wv[c], acc[r][c]);
        }
        __syncthreads();
    }

    float asv[4], adv[4];
    *(float4*)asv = *(const float4*)&att_src[cg * 4];
    *(float4*)adv = *(const float4*)&att_dst[cg * 4];
    const int head = cg >> 2;

    #pragma unroll
    for (int r = 0; r < 4; ++r) {
        int row = row0 + rg * 4 + r;
        float s = acc[r][0]*asv[0] + acc[r][1]*asv[1] + acc[r][2]*asv[2] + acc[r][3]*asv[3];
        float d = acc[r][0]*adv[0] + acc[r][1]*adv[1] + acc[r][2]*adv[2] + acc[r][3]*adv[3];
        s += __shfl_xor(s, 1, 4); s += __shfl_xor(s, 2, 4);
        d += __shfl_xor(d, 1, 4); d += __shfl_xor(d, 2, 4);
        if (row < N) {
            uint2 pw = make_uint2(pack_bf16x2(acc[r][0], acc[r][1]),
                                  pack_bf16x2(acc[r][2], acc[r][3]));
            *(uint2*)&h1p[(size_t)row * H1W + cg * 2] = pw;
            if ((cg & 3) == 0) {
                h1p[(size_t)row * H1W + 64 + head] = __float_as_uint(s);
                ad1[row * 8 + head] = d;
            }
        }
    }
}

// ---------------- GEMM2: h2p(bf16,stride 36w) = h @ W2, a_src packed at word 32 ----------------
__global__ __launch_bounds__(256) void gemm2_kernel(
    const float* __restrict__ h, const float* __restrict__ W,
    const float* __restrict__ att_src, const float* __restrict__ att_dst,
    uint32_t* __restrict__ h2p, float* __restrict__ ad2, int N)
{
    __shared__ __align__(16) float Wsh[32 * 64];
    __shared__ __align__(16) float xT[32 * 68];
    const int t  = threadIdx.x;
    const int cg = t & 15;
    const int rg = t >> 4;
    const int row0 = blockIdx.x * 64;

    float acc[4][4] = {};
    for (int kk = 0; kk < 128; kk += 32) {
        for (int i = t; i < 32 * 64; i += 256) {
            int kl = i >> 6, c = i & 63;
            Wsh[i] = W[(kk + kl) * 64 + c];
        }
        for (int i = t; i < 64 * 32; i += 256) {
            int r = i >> 5, kl = i & 31;
            int row = row0 + r;
            xT[kl * 68 + r] = (row < N) ? h[(size_t)row * 128 + kk + kl] : 0.0f;
        }
        __syncthreads();
        #pragma unroll
        for (int kl = 0; kl < 32; ++kl) {
            float xv[4], wv[4];
            *(float4*)xv = *(const float4*)&xT[kl * 68 + rg * 4];
            *(float4*)wv = *(const float4*)&Wsh[kl * 64 + cg * 4];
            #pragma unroll
            for (int r = 0; r < 4; ++r)
                #pragma unroll
                for (int c = 0; c < 4; ++c)
                    acc[r][c] = fmaf(xv[r], wv[c], acc[r][c]);
        }
        __syncthreads();
    }

    float asv[4], adv[4];
    *(float4*)asv = *(const float4*)&att_src[cg * 4];
    *(float4*)adv = *(const float4*)&att_dst[cg * 4];

    #pragma unroll
    for (int r = 0; r < 4; ++r) {
        int row = row0 + rg * 4 + r;
        float s = acc[r][0]*asv[0] + acc[r][1]*asv[1] + acc[r][2]*asv[2] + acc[r][3]*asv[3];
        float d = acc[r][0]*adv[0] + acc[r][1]*adv[1] + acc[r][2]*adv[2] + acc[r][3]*adv[3];
        #pragma unroll
        for (int off = 1; off < 16; off <<= 1) {
            s += __shfl_xor(s, off, 16);
            d += __shfl_xor(d, off, 16);
        }
        if (row < N) {
            uint2 pw = make_uint2(pack_bf16x2(acc[r][0], acc[r][1]),
                                  pack_bf16x2(acc[r][2], acc[r][3]));
            *(uint2*)&h2p[(size_t)row * H2W + cg * 2] = pw;
            if (cg == 0) { h2p[(size_t)row * H2W + 32] = __float_as_uint(s); ad2[row] = d; }
        }
    }
}

// ---------------- bucket sort pass 1a: per-block bucket histogram (no atomics to HBM) ----------------
__global__ __launch_bounds__(256) void p1_count_kernel(
    const int* __restrict__ ei, int* __restrict__ pbh, int E, int NB, int chunk)
{
    __shared__ int hist[NBMAX];
    int t = threadIdx.x;
    if (t < NB) hist[t] = 0;
    __syncthreads();
    int e0 = blockIdx.x * chunk;
    int e1 = min(E, e0 + chunk);
    for (int e = e0 + t; e < e1; e += 256)
        atomicAdd(&hist[ei[E + e] >> 9], 1);
    __syncthreads();
    if (t < NB) pbh[t * NBLK1 + blockIdx.x] = hist[t];   // bucket-major
}

// ---------------- pass 1b: scan bucket totals; rewrite pbh to absolute bases ----------------
__global__ __launch_bounds__(256) void p1_scan_kernel(
    int* __restrict__ pbh, int* __restrict__ bucket_base, int NB, int E)
{
    __shared__ int ps[256];
    int t = threadIdx.x;
    int s = 0;
    if (t < NB) {
        const int* row = &pbh[t * NBLK1];
        for (int b = 0; b < NBLK1; ++b) s += row[b];
    }
    ps[t] = s; __syncthreads();
    for (int off = 1; off < 256; off <<= 1) {
        int add = (t >= off) ? ps[t - off] : 0;
        __syncthreads();
        ps[t] += add;
        __syncthreads();
    }
    int base = ps[t] - s;   // exclusive
    if (t < NB) {
        bucket_base[t] = base;
        int* row = &pbh[t * NBLK1];
        int run = base;
        for (int b = 0; b < NBLK1; ++b) {
            int c = row[b];
            row[b] = run;
            run += c;
        }
    }
    if (t == 0) bucket_base[NB] = E;
}

// ---------------- pass 1c: place edges into bucket regions (packed src|dst_local) ----------------
__global__ __launch_bounds__(256) void p1_place_kernel(
    const int* __restrict__ ei, const int* __restrict__ pbh,
    uint32_t* __restrict__ staging, int E, int NB, int chunk)
{
    __shared__ int lcur[NBMAX];
    int t = threadIdx.x;
    if (t < NB) lcur[t] = pbh[t * NBLK1 + blockIdx.x];
    __syncthreads();
    int e0 = blockIdx.x * chunk;
    int e1 = min(E, e0 + chunk);
    for (int e = e0 + t; e < e1; e += 256) {
        int s = ei[e], d = ei[E + e];
        int b = d >> 9;
        int p = atomicAdd(&lcur[b], 1);          // LDS atomic
        staging[p] = ((uint32_t)s << 9) | (uint32_t)(d & 511);
    }
}

// ---------------- pass 2: per-bucket CSR build (row_start + sorted_src) ----------------
__global__ __launch_bounds__(256) void p2_build_kernel(
    const uint32_t* __restrict__ staging, const int* __restrict__ bucket_base,
    int* __restrict__ row_start, int* __restrict__ sorted_src, int N, int E, int NB)
{
    __shared__ int cnt[NPB];
    __shared__ int ofs[NPB];
    __shared__ int ps[256];
    int b = blockIdx.x, t = threadIdx.x;
    int base = bucket_base[b], end = bucket_base[b + 1];
    cnt[t] = 0; cnt[t + 256] = 0;
    __syncthreads();
    for (int i = base + t; i < end; i += 256)
        atomicAdd(&cnt[staging[i] & 511], 1);
    __syncthreads();
    // exclusive scan over 512: pairwise + Hillis-Steele over 256
    int c0 = cnt[2 * t], c1 = cnt[2 * t + 1];
    int p = c0 + c1;
    ps[t] = p; __syncthreads();
    for (int off = 1; off < 256; off <<= 1) {
        int add = (t >= off) ? ps[t - off] : 0;
        __syncthreads();
        ps[t] += add;
        __syncthreads();
    }
    int pex = ps[t] - p;
    ofs[2 * t] = pex;
    ofs[2 * t + 1] = pex + c0;
    __syncthreads();
    // row_start (coalesced)
    int node0 = b * NPB;
    #pragma unroll
    for (int i = t; i < NPB; i += 256) {
        int node = node0 + i;
        if (node < N) row_start[node] = base + ofs[i];
    }
    if (b == NB - 1 && t == 0) row_start[N] = E;
    __syncthreads();
    // place src (scatter confined to this bucket's ~L2-hot output range)
    for (int i = base + t; i < end; i += 256) {
        uint32_t v = staging[i];
        int nl = v & 511;
        int pos = base + atomicAdd(&ofs[nl], 1);   // LDS atomic
        sorted_src[pos] = (int)(v >> 9);
    }
}

// ---------------- gather layer 1 (bf16): hbuf = elu(softmax-weighted sum + b1) ----------------
__global__ __launch_bounds__(256) void gather1_kernel(
    const int* __restrict__ row_start, const int* __restrict__ sorted_src,
    const float* __restrict__ ad1, const uint32_t* __restrict__ h1p,
    const float* __restrict__ b1, float* __restrict__ hbuf, int N)
{
    int node = blockIdx.x * 4 + (threadIdx.x >> 6);
    if (node >= N) return;
    int cw = threadIdx.x & 63;        // channel-word: channels 2cw, 2cw+1
    int hh = cw >> 3;                 // 8 words per head
    int r0 = row_start[node], r1 = row_start[node + 1];
    float ad = ad1[node * 8 + hh];
    float acc0 = 0.0f, acc1 = 0.0f, den = 0.0f;
    for (int j = r0; j < r1; j += 4) {
        int  srcs[4];
        bool valid[4];
        #pragma unroll
        for (int k = 0; k < 4; ++k) {
            int jj = j + k;
            valid[k] = jj < r1;
            srcs[k] = sorted_src[valid[k] ? jj : r0];
        }
        float    av[4];
        uint32_t hv[4];
        #pragma unroll
        for (int k = 0; k < 4; ++k) {
            size_t base = (size_t)srcs[k] * H1W;
            av[k] = __uint_as_float(h1p[base + 64 + hh]);
            hv[k] = h1p[base + cw];
        }
        #pragma unroll
        for (int k = 0; k < 4; ++k) {
            float ev = av[k] + ad;
            ev = ev > 0.0f ? ev : SLOPE * ev;
            float w = valid[k] ? __expf(ev) : 0.0f;
            den += w;
            float lo = __uint_as_float(hv[k] << 16);
            float hi = __uint_as_float(hv[k] & 0xffff0000u);
            acc0 = fmaf(w, lo, acc0);
            acc1 = fmaf(w, hi, acc1);
        }
    }
    float inv = 1.0f / (den + EPSV);
    float v0 = acc0 * inv + b1[cw * 2];
    float v1 = acc1 * inv + b1[cw * 2 + 1];
    v0 = v0 > 0.0f ? v0 : expm1f(v0);
    v1 = v1 > 0.0f ? v1 : expm1f(v1);
    *(float2*)&hbuf[(size_t)node * 128 + cw * 2] = make_float2(v0, v1);
}

// ---------------- gather layer 2 (bf16): out = b2 + softmax-weighted sum ----------------
__global__ __launch_bounds__(256) void gather2_kernel(
    const int* __restrict__ row_start, const int* __restrict__ sorted_src,
    const float* __restrict__ ad2, const uint32_t* __restrict__ h2p,
    const float* __restrict__ b2, float* __restrict__ out, int N)
{
    int node = blockIdx.x * 8 + (threadIdx.x >> 5);
    if (node >= N) return;
    int cw = threadIdx.x & 31;        // channels 2cw, 2cw+1
    int r0 = row_start[node], r1 = row_start[node + 1];
    float ad = ad2[node];
    float acc0 = 0.0f, acc1 = 0.0f, den = 0.0f;
    for (int j = r0; j < r1; j += 4) {
        int  srcs[4];
        bool valid[4];
        #pragma unroll
        for (int k = 0; k < 4; ++k) {
            int jj = j + k;
            valid[k] = jj < r1;
            srcs[k] = sorted_src[valid[k] ? jj : r0];
        }
        float    av[4];
        uint32_t hv[4];
        #pragma unroll
        for (int k = 0; k < 4; ++k) {
            size_t base = (size_t)srcs[k] * H2W;
            av[k] = __uint_as_float(h2p[base + 32]);
            hv[k] = h2p[base + cw];
        }
        #pragma unroll
        for (int k = 0; k < 4; ++k) {
            float ev = av[k] + ad;
            ev = ev > 0.0f ? ev : SLOPE * ev;
            float w = valid[k] ? __expf(ev) : 0.0f;
            den += w;
            float lo = __uint_as_float(hv[k] << 16);
            float hi = __uint_as_float(hv[k] & 0xffff0000u);
            acc0 = fmaf(w, lo, acc0);
            acc1 = fmaf(w, hi, acc1);
        }
    }
    float inv = 1.0f / (den + EPSV);
    *(float2*)&out[(size_t)node * 64 + cw * 2] =
        make_float2(acc0 * inv + b2[cw * 2], acc1 * inv + b2[cw * 2 + 1]);
}

extern "C" void kernel_launch(void* const* d_in, const int* in_sizes, int n_in,
                              void* d_out, int out_size, void* d_ws, size_t ws_size,
                              hipStream_t stream)
{
    const int N = in_sizes[0] / 128;
    const int E = in_sizes[1] / 2;
    const int NB = (N + NPB - 1) / NPB;          // 196 for N=100k
    const int chunk = (E + NBLK1 - 1) / NBLK1;

    const float* x        = (const float*)d_in[0];
    const int*   ei       = (const int*)  d_in[1];
    const float* W1       = (const float*)d_in[2];
    const float* att_src1 = (const float*)d_in[3];
    const float* att_dst1 = (const float*)d_in[4];
    const float* b1       = (const float*)d_in[5];
    const float* W2       = (const float*)d_in[6];
    const float* att_src2 = (const float*)d_in[7];
    const float* att_dst2 = (const float*)d_in[8];
    const float* b2       = (const float*)d_in[9];
    float* out = (float*)d_out;

    uint32_t* h1p  = (uint32_t*)d_ws;                 // N*72 words (reused as h2p N*36)
    float* hbuf    = (float*)(h1p + (size_t)N * H1W); // N*128
    float* ad1     = hbuf + (size_t)N * 128;          // N*8
    float* ad2     = ad1  + (size_t)N * 8;            // N
    int* row_start   = (int*)(ad2 + N);               // N+1
    int* bucket_base = row_start + (N + 1);           // NB+1
    int* pbh         = bucket_base + (NB + 1);        // NB*NBLK1
    int* sorted_src  = pbh + NB * NBLK1;              // E
    uint32_t* staging = (uint32_t*)(sorted_src + E);  // E
    uint32_t* h2p   = h1p;                            // alias: h1p dead after gather1

    // --- bucket counting sort by dst (no global atomics) ---
    p1_count_kernel<<<NBLK1, 256, 0, stream>>>(ei, pbh, E, NB, chunk);
    p1_scan_kernel <<<1, 256, 0, stream>>>(pbh, bucket_base, NB, E);
    p1_place_kernel<<<NBLK1, 256, 0, stream>>>(ei, pbh, staging, E, NB, chunk);
    p2_build_kernel<<<NB, 256, 0, stream>>>(staging, bucket_base, row_start, sorted_src, N, E, NB);

    // --- layer 1 ---
    gemm1_kernel<<<(N + 31) / 32, 256, 0, stream>>>(x, W1, att_src1, att_dst1, h1p, ad1, N);
    gather1_kernel<<<(N + 3) / 4, 256, 0, stream>>>(row_start, sorted_src, ad1, h1p, b1, hbuf, N);

    // --- layer 2 ---
    gemm2_kernel<<<(N + 63) / 64, 256, 0, stream>>>(hbuf, W2, att_src2, att_dst2, h2p, ad2, N);
    gather2_kernel<<<(N + 7) / 8, 256, 0, stream>>>(row_start, sorted_src, ad2, h2p, b2, out, N);
}

// Round 6
// 314.337 us; speedup vs baseline: 6.0725x; 1.0857x over previous
//
#include <hip/hip_runtime.h>
#include <hip/hip_bf16.h>
#include <stdint.h>

#define SLOPE 0.2f
#define EPSV 1e-16f
#define H1W 72    // row stride in u32 words: 64 bf16x2 words + 8 fp32 a_src
#define H2W 36    // 32 bf16x2 words + 1 fp32 a_src + 3 pad

#define NPB   512   // nodes per bucket (pow2); bucket = dst >> 9
#define NBMAX 256   // max buckets (N <= 131072)
#define NBLK1 256   // pass-1 blocks

static __device__ __forceinline__ uint32_t pack_bf16x2(float a, float b) {
    uint32_t ua = __float_as_uint(a), ub = __float_as_uint(b);
    ua = (ua + 0x7fffu + ((ua >> 16) & 1u)) >> 16;   // RTNE
    ub = (ub + 0x7fffu + ((ub >> 16) & 1u)) >> 16;
    return ua | (ub << 16);
}

// ---------------- GEMM1: h1p(bf16,stride 72w) = x @ W1, a_src packed at word 64 ----------------
__global__ __launch_bounds__(256) void gemm1_kernel(
    const float* __restrict__ x, const float* __restrict__ W,
    const float* __restrict__ att_src, const float* __restrict__ att_dst,
    uint32_t* __restrict__ h1p, float* __restrict__ ad1, int N)
{
    __shared__ __align__(16) float Wsh[32 * 128];
    __shared__ __align__(16) float xT[32 * 36];
    const int t  = threadIdx.x;
    const int cg = t & 31;
    const int rg = t >> 5;
    const int row0 = blockIdx.x * 32;

    float acc[4][4] = {};
    for (int kk = 0; kk < 128; kk += 32) {
        for (int i = t; i < 32 * 128; i += 256) {
            int kl = i >> 7, c = i & 127;
            Wsh[i] = W[(kk + kl) * 128 + c];
        }
        for (int i = t; i < 32 * 32; i += 256) {
            int r = i >> 5, kl = i & 31;
            int row = row0 + r;
            xT[kl * 36 + r] = (row < N) ? x[(size_t)row * 128 + kk + kl] : 0.0f;
        }
        __syncthreads();
        #pragma unroll
        for (int kl = 0; kl < 32; ++kl) {
            float xv[4], wv[4];
            *(float4*)xv = *(const float4*)&xT[kl * 36 + rg * 4];
            *(float4*)wv = *(const float4*)&Wsh[kl * 128 + cg * 4];
            #pragma unroll
            for (int r = 0; r < 4; ++r)
                #pragma unroll
                for (int c = 0; c < 4; ++c)
                    acc[r][c] = fmaf(xv[r], wv[c], acc[r][c]);
        }
        __syncthreads();
    }

    float asv[4], adv[4];
    *(float4*)asv = *(const float4*)&att_src[cg * 4];
    *(float4*)adv = *(const float4*)&att_dst[cg * 4];
    const int head = cg >> 2;

    #pragma unroll
    for (int r = 0; r < 4; ++r) {
        int row = row0 + rg * 4 + r;
        float s = acc[r][0]*asv[0] + acc[r][1]*asv[1] + acc[r][2]*asv[2] + acc[r][3]*asv[3];
        float d = acc[r][0]*adv[0] + acc[r][1]*adv[1] + acc[r][2]*adv[2] + acc[r][3]*adv[3];
        s += __shfl_xor(s, 1, 4); s += __shfl_xor(s, 2, 4);
        d += __shfl_xor(d, 1, 4); d += __shfl_xor(d, 2, 4);
        if (row < N) {
            uint2 pw = make_uint2(pack_bf16x2(acc[r][0], acc[r][1]),
                                  pack_bf16x2(acc[r][2], acc[r][3]));
            *(uint2*)&h1p[(size_t)row * H1W + cg * 2] = pw;
            if ((cg & 3) == 0) {
                h1p[(size_t)row * H1W + 64 + head] = __float_as_uint(s);
                ad1[row * 8 + head] = d;
            }
        }
    }
}

// ---------------- GEMM2: h2p(bf16,stride 36w) = h @ W2, a_src packed at word 32 ----------------
__global__ __launch_bounds__(256) void gemm2_kernel(
    const float* __restrict__ h, const float* __restrict__ W,
    const float* __restrict__ att_src, const float* __restrict__ att_dst,
    uint32_t* __restrict__ h2p, float* __restrict__ ad2, int N)
{
    __shared__ __align__(16) float Wsh[32 * 64];
    __shared__ __align__(16) float xT[32 * 68];
    const int t  = threadIdx.x;
    const int cg = t & 15;
    const int rg = t >> 4;
    const int row0 = blockIdx.x * 64;

    float acc[4][4] = {};
    for (int kk = 0; kk < 128; kk += 32) {
        for (int i = t; i < 32 * 64; i += 256) {
            int kl = i >> 6, c = i & 63;
            Wsh[i] = W[(kk + kl) * 64 + c];
        }
        for (int i = t; i < 64 * 32; i += 256) {
            int r = i >> 5, kl = i & 31;
            int row = row0 + r;
            xT[kl * 68 + r] = (row < N) ? h[(size_t)row * 128 + kk + kl] : 0.0f;
        }
        __syncthreads();
        #pragma unroll
        for (int kl = 0; kl < 32; ++kl) {
            float xv[4], wv[4];
            *(float4*)xv = *(const float4*)&xT[kl * 68 + rg * 4];
            *(float4*)wv = *(const float4*)&Wsh[kl * 64 + cg * 4];
            #pragma unroll
            for (int r = 0; r < 4; ++r)
                #pragma unroll
                for (int c = 0; c < 4; ++c)
                    acc[r][c] = fmaf(xv[r], wv[c], acc[r][c]);
        }
        __syncthreads();
    }

    float asv[4], adv[4];
    *(float4*)asv = *(const float4*)&att_src[cg * 4];
    *(float4*)adv = *(const float4*)&att_dst[cg * 4];

    #pragma unroll
    for (int r = 0; r < 4; ++r) {
        int row = row0 + rg * 4 + r;
        float s = acc[r][0]*asv[0] + acc[r][1]*asv[1] + acc[r][2]*asv[2] + acc[r][3]*asv[3];
        float d = acc[r][0]*adv[0] + acc[r][1]*adv[1] + acc[r][2]*adv[2] + acc[r][3]*adv[3];
        #pragma unroll
        for (int off = 1; off < 16; off <<= 1) {
            s += __shfl_xor(s, off, 16);
            d += __shfl_xor(d, off, 16);
        }
        if (row < N) {
            uint2 pw = make_uint2(pack_bf16x2(acc[r][0], acc[r][1]),
                                  pack_bf16x2(acc[r][2], acc[r][3]));
            *(uint2*)&h2p[(size_t)row * H2W + cg * 2] = pw;
            if (cg == 0) { h2p[(size_t)row * H2W + 32] = __float_as_uint(s); ad2[row] = d; }
        }
    }
}

// ---------------- bucket sort pass 1a: per-block bucket histogram ----------------
__global__ __launch_bounds__(256) void p1_count_kernel(
    const int* __restrict__ ei, int* __restrict__ pbh, int E, int NB, int chunk)
{
    __shared__ int hist[NBMAX];
    int t = threadIdx.x;
    if (t < NB) hist[t] = 0;
    __syncthreads();
    int e0 = blockIdx.x * chunk;
    int e1 = min(E, e0 + chunk);
    for (int e = e0 + t; e < e1; e += 256)
        atomicAdd(&hist[ei[E + e] >> 9], 1);
    __syncthreads();
    if (t < NB) pbh[t * NBLK1 + blockIdx.x] = hist[t];   // bucket-major
}

// ---------------- pass 1b: scan bucket totals; rewrite pbh to absolute bases ----------------
__global__ __launch_bounds__(256) void p1_scan_kernel(
    int* __restrict__ pbh, int* __restrict__ bucket_base, int NB, int E)
{
    __shared__ int ps[256];
    int t = threadIdx.x;
    int s = 0;
    if (t < NB) {
        const int* row = &pbh[t * NBLK1];
        for (int b = 0; b < NBLK1; ++b) s += row[b];
    }
    ps[t] = s; __syncthreads();
    for (int off = 1; off < 256; off <<= 1) {
        int add = (t >= off) ? ps[t - off] : 0;
        __syncthreads();
        ps[t] += add;
        __syncthreads();
    }
    int base = ps[t] - s;   // exclusive
    if (t < NB) {
        bucket_base[t] = base;
        int* row = &pbh[t * NBLK1];
        int run = base;
        for (int b = 0; b < NBLK1; ++b) {
            int c = row[b];
            row[b] = run;
            run += c;
        }
    }
    if (t == 0) bucket_base[NB] = E;
}

// ---------------- pass 1c: place edges into bucket regions (packed src|dst_local) ----------------
__global__ __launch_bounds__(256) void p1_place_kernel(
    const int* __restrict__ ei, const int* __restrict__ pbh,
    uint32_t* __restrict__ staging, int E, int NB, int chunk)
{
    __shared__ int lcur[NBMAX];
    int t = threadIdx.x;
    if (t < NB) lcur[t] = pbh[t * NBLK1 + blockIdx.x];
    __syncthreads();
    int e0 = blockIdx.x * chunk;
    int e1 = min(E, e0 + chunk);
    for (int e = e0 + t; e < e1; e += 256) {
        int s = ei[e], d = ei[E + e];
        int b = d >> 9;
        int p = atomicAdd(&lcur[b], 1);          // LDS atomic
        staging[p] = ((uint32_t)s << 9) | (uint32_t)(d & 511);
    }
}

// ---------------- pass 2: per-bucket CSR build (row_start + sorted_src) ----------------
__global__ __launch_bounds__(256) void p2_build_kernel(
    const uint32_t* __restrict__ staging, const int* __restrict__ bucket_base,
    int* __restrict__ row_start, int* __restrict__ sorted_src, int N, int E, int NB)
{
    __shared__ int cnt[NPB];
    __shared__ int ofs[NPB];
    __shared__ int ps[256];
    int b = blockIdx.x, t = threadIdx.x;
    int base = bucket_base[b], end = bucket_base[b + 1];
    cnt[t] = 0; cnt[t + 256] = 0;
    __syncthreads();
    for (int i = base + t; i < end; i += 256)
        atomicAdd(&cnt[staging[i] & 511], 1);
    __syncthreads();
    int c0 = cnt[2 * t], c1 = cnt[2 * t + 1];
    int p = c0 + c1;
    ps[t] = p; __syncthreads();
    for (int off = 1; off < 256; off <<= 1) {
        int add = (t >= off) ? ps[t - off] : 0;
        __syncthreads();
        ps[t] += add;
        __syncthreads();
    }
    int pex = ps[t] - p;
    ofs[2 * t] = pex;
    ofs[2 * t + 1] = pex + c0;
    __syncthreads();
    int node0 = b * NPB;
    #pragma unroll
    for (int i = t; i < NPB; i += 256) {
        int node = node0 + i;
        if (node < N) row_start[node] = base + ofs[i];
    }
    if (b == NB - 1 && t == 0) row_start[N] = E;
    __syncthreads();
    for (int i = base + t; i < end; i += 256) {
        uint32_t v = staging[i];
        int nl = v & 511;
        int pos = base + atomicAdd(&ofs[nl], 1);   // LDS atomic
        sorted_src[pos] = (int)(v >> 9);
    }
}

// ---------------- gather layer 1 (bf16, lane-specialized weights) ----------------
// 256 threads = 4 nodes x 64 lanes (one wave per node).
// Edge groups of 8: lane l computes weight for (edge j+(l>>3), head l&7);
// fma path reads weights/offsets via __shfl.
__global__ __launch_bounds__(256) void gather1_kernel(
    const int* __restrict__ row_start, const int* __restrict__ sorted_src,
    const float* __restrict__ ad1, const uint32_t* __restrict__ h1p,
    const float* __restrict__ b1, float* __restrict__ hbuf, int N)
{
    int node = blockIdx.x * 4 + (threadIdx.x >> 6);
    if (node >= N) return;
    int lane = threadIdx.x & 63;
    int cw = lane;                 // channel-word: channels 2cw, 2cw+1
    int hh = lane >> 3;            // fma-duty head
    int wh = lane & 7;             // weight-duty head
    int r0 = row_start[node], r1 = row_start[node + 1];
    float ad_w = ad1[node * 8 + wh];
    const uint32_t* pch = h1p + cw;        // fma-duty channel column
    float acc0 = 0.0f, acc1 = 0.0f, den = 0.0f;

    for (int j = r0; j < r1; j += 8) {
        int jw = j + (lane >> 3);          // weight-duty edge
        bool vw = jw < r1;
        int sw = sorted_src[vw ? jw : r0];
        int swoff = sw * H1W;
        float av = __uint_as_float(h1p[swoff + 64 + wh]);
        float ev = av + ad_w;
        ev = ev > 0.0f ? ev : SLOPE * ev;
        float w = vw ? __expf(ev) : 0.0f;

        #pragma unroll
        for (int k = 0; k < 8; ++k) {
            float wk   = __shfl(w,     k * 8 + hh, 64);  // weight(edge j+k, head hh)
            int   offk = __shfl(swoff, k * 8 + wh, 64);  // row offset of edge j+k
            uint32_t hv = pch[offk];
            den += wk;
            acc0 = fmaf(wk, __uint_as_float(hv << 16), acc0);
            acc1 = fmaf(wk, __uint_as_float(hv & 0xffff0000u), acc1);
        }
    }
    float inv = 1.0f / (den + EPSV);
    float v0 = acc0 * inv + b1[cw * 2];
    float v1 = acc1 * inv + b1[cw * 2 + 1];
    v0 = v0 > 0.0f ? v0 : expm1f(v0);
    v1 = v1 > 0.0f ? v1 : expm1f(v1);
    *(float2*)&hbuf[(size_t)node * 128 + cw * 2] = make_float2(v0, v1);
}

// ---------------- gather layer 2 (bf16, lane-specialized weights) ----------------
// 256 threads = 8 nodes x 32 lanes; width-32 shuffles.
__global__ __launch_bounds__(256) void gather2_kernel(
    const int* __restrict__ row_start, const int* __restrict__ sorted_src,
    const float* __restrict__ ad2, const uint32_t* __restrict__ h2p,
    const float* __restrict__ b2, float* __restrict__ out, int N)
{
    int node = blockIdx.x * 8 + (threadIdx.x >> 5);
    if (node >= N) return;
    int lane = threadIdx.x & 31;
    int cw = lane;                 // channels 2cw, 2cw+1
    int r0 = row_start[node], r1 = row_start[node + 1];
    float ad = ad2[node];
    const uint32_t* pch = h2p + cw;
    float acc0 = 0.0f, acc1 = 0.0f, den = 0.0f;

    for (int j = r0; j < r1; j += 8) {
        int jw = j + (lane & 7);           // weight-duty edge (4x redundant)
        bool vw = jw < r1;
        int sw = sorted_src[vw ? jw : r0];
        int swoff = sw * H2W;
        float av = __uint_as_float(h2p[swoff + 32]);
        float ev = av + ad;
        ev = ev > 0.0f ? ev : SLOPE * ev;
        float w = vw ? __expf(ev) : 0.0f;

        #pragma unroll
        for (int k = 0; k < 8; ++k) {
            float wk   = __shfl(w,     k, 32);   // lane k of this 32-seg: edge j+k
            int   offk = __shfl(swoff, k, 32);
            uint32_t hv = pch[offk];
            den += wk;
            acc0 = fmaf(wk, __uint_as_float(hv << 16), acc0);
            acc1 = fmaf(wk, __uint_as_float(hv & 0xffff0000u), acc1);
        }
    }
    float inv = 1.0f / (den + EPSV);
    *(float2*)&out[(size_t)node * 64 + cw * 2] =
        make_float2(acc0 * inv + b2[cw * 2], acc1 * inv + b2[cw * 2 + 1]);
}

extern "C" void kernel_launch(void* const* d_in, const int* in_sizes, int n_in,
                              void* d_out, int out_size, void* d_ws, size_t ws_size,
                              hipStream_t stream)
{
    const int N = in_sizes[0] / 128;
    const int E = in_sizes[1] / 2;
    const int NB = (N + NPB - 1) / NPB;
    const int chunk = (E + NBLK1 - 1) / NBLK1;

    const float* x        = (const float*)d_in[0];
    const int*   ei       = (const int*)  d_in[1];
    const float* W1       = (const float*)d_in[2];
    const float* att_src1 = (const float*)d_in[3];
    const float* att_dst1 = (const float*)d_in[4];
    const float* b1       = (const float*)d_in[5];
    const float* W2       = (const float*)d_in[6];
    const float* att_src2 = (const float*)d_in[7];
    const float* att_dst2 = (const float*)d_in[8];
    const float* b2       = (const float*)d_in[9];
    float* out = (float*)d_out;

    uint32_t* h1p  = (uint32_t*)d_ws;                 // N*72 words (reused as h2p N*36)
    float* hbuf    = (float*)(h1p + (size_t)N * H1W); // N*128
    float* ad1     = hbuf + (size_t)N * 128;          // N*8
    float* ad2     = ad1  + (size_t)N * 8;            // N
    int* row_start   = (int*)(ad2 + N);               // N+1
    int* bucket_base = row_start + (N + 1);           // NB+1
    int* pbh         = bucket_base + (NB + 1);        // NB*NBLK1
    int* sorted_src  = pbh + NB * NBLK1;              // E
    uint32_t* staging = (uint32_t*)(sorted_src + E);  // E
    uint32_t* h2p   = h1p;                            // alias: h1p dead after gather1

    // --- bucket counting sort by dst (no global atomics) ---
    p1_count_kernel<<<NBLK1, 256, 0, stream>>>(ei, pbh, E, NB, chunk);
    p1_scan_kernel <<<1, 256, 0, stream>>>(pbh, bucket_base, NB, E);
    p1_place_kernel<<<NBLK1, 256, 0, stream>>>(ei, pbh, staging, E, NB, chunk);
    p2_build_kernel<<<NB, 256, 0, stream>>>(staging, bucket_base, row_start, sorted_src, N, E, NB);

    // --- layer 1 ---
    gemm1_kernel<<<(N + 31) / 32, 256, 0, stream>>>(x, W1, att_src1, att_dst1, h1p, ad1, N);
    gather1_kernel<<<(N + 3) / 4, 256, 0, stream>>>(row_start, sorted_src, ad1, h1p, b1, hbuf, N);

    // --- layer 2 ---
    gemm2_kernel<<<(N + 63) / 64, 256, 0, stream>>>(hbuf, W2, att_src2, att_dst2, h2p, ad2, N);
    gather2_kernel<<<(N + 7) / 8, 256, 0, stream>>>(row_start, sorted_src, ad2, h2p, b2, out, N);
}

// Round 7
// 281.128 us; speedup vs baseline: 6.7899x; 1.1181x over previous
//
#include <hip/hip_runtime.h>
#include <hip/hip_bf16.h>
#include <stdint.h>

#define SLOPE 0.2f
#define EPSV 1e-16f
#define H1W 72    // h1p row stride in u32 words: 64 bf16x2 words + 8 fp32 a_src
#define H2W 36    // 32 bf16x2 words + 1 fp32 a_src + 3 pad

#define NPB   512   // nodes per bucket (pow2); bucket = dst >> 9
#define NBMAX 256   // max buckets (N <= 131072)
#define NBLK1 256   // pass-1 blocks

typedef __attribute__((ext_vector_type(8))) short bf16x8;
typedef __attribute__((ext_vector_type(4))) float f32x4;

static __device__ __forceinline__ uint32_t cvtpk(float a, float b) {
    uint32_t r;
    asm("v_cvt_pk_bf16_f32 %0, %1, %2" : "=v"(r) : "v"(a), "v"(b));
    return r;
}
static __device__ __forceinline__ float lof(uint32_t u) { return __uint_as_float(u << 16); }
static __device__ __forceinline__ float hif(uint32_t u) { return __uint_as_float(u & 0xffff0000u); }

union FragCvt { uint4 u; bf16x8 f; };

// ---------------- prep: W1,W2 -> transposed bf16 hi/lo tables WT[n][k] ----------------
__global__ __launch_bounds__(256) void prep_kernel(
    const float* __restrict__ W1, const float* __restrict__ W2,
    uint32_t* __restrict__ wt1hi, uint32_t* __restrict__ wt1lo,
    uint32_t* __restrict__ wt2hi, uint32_t* __restrict__ wt2lo)
{
    int t = threadIdx.x;
    if (blockIdx.x == 0) {
        for (int i = t; i < 128 * 64; i += 256) {
            int n = i >> 6, kp = i & 63;
            float w0 = W1[(2 * kp) * 128 + n], w1 = W1[(2 * kp + 1) * 128 + n];
            uint32_t h = cvtpk(w0, w1);
            wt1hi[n * 64 + kp] = h;
            wt1lo[n * 64 + kp] = cvtpk(w0 - lof(h), w1 - hif(h));
        }
    } else {
        for (int i = t; i < 64 * 64; i += 256) {
            int n = i >> 6, kp = i & 63;
            float w0 = W2[(2 * kp) * 64 + n], w1 = W2[(2 * kp + 1) * 64 + n];
            uint32_t h = cvtpk(w0, w1);
            wt2hi[n * 64 + kp] = h;
            wt2lo[n * 64 + kp] = cvtpk(w0 - lof(h), w1 - hif(h));
        }
    }
}

// ---------------- GEMM1 (MFMA split-precision): h1p = x @ W1, fused a_s/a_d ----------------
// 256 thr = 4 waves x 32 rows (2 row-tiles of 16). N=128 (8 col-tiles). K=128 in 2 LDS halves.
__global__ __launch_bounds__(256) void gemm1_mfma(
    const float* __restrict__ x,
    const uint32_t* __restrict__ wthi, const uint32_t* __restrict__ wtlo,
    const float* __restrict__ att_src, const float* __restrict__ att_dst,
    uint32_t* __restrict__ h1p, float* __restrict__ ad1, int N)
{
    __shared__ uint32_t lds[2][128 * 36];   // [hi/lo][col*36 + k_u32], stride 144B (16B-aligned)
    const int t = threadIdx.x;
    const int w = t >> 6, l = t & 63;
    const int cl = l & 15, rg = l >> 4;     // rg in 0..3
    const int rowbase = blockIdx.x * 128 + w * 32;

    f32x4 zero = {0.f, 0.f, 0.f, 0.f};
    f32x4 acc[2][8];
    #pragma unroll
    for (int rt = 0; rt < 2; ++rt)
        #pragma unroll
        for (int tl = 0; tl < 8; ++tl) acc[rt][tl] = zero;

    for (int kh = 0; kh < 2; ++kh) {
        if (kh) __syncthreads();
        for (int i = t; i < 1024; i += 256) {
            int col = i >> 3, q = i & 7;
            *(uint4*)&lds[0][col * 36 + q * 4] = *(const uint4*)&wthi[col * 64 + kh * 32 + q * 4];
            *(uint4*)&lds[1][col * 36 + q * 4] = *(const uint4*)&wtlo[col * 64 + kh * 32 + q * 4];
        }
        __syncthreads();
        #pragma unroll
        for (int ks = 0; ks < 2; ++ks) {
            const int kg = kh * 64 + ks * 32 + rg * 8;
            bf16x8 ahi[2], alo[2];
            #pragma unroll
            for (int rt = 0; rt < 2; ++rt) {
                int row = rowbase + rt * 16 + cl;
                row = min(row, N - 1);
                const float* xr = x + (size_t)row * 128 + kg;
                float4 v0 = *(const float4*)xr;
                float4 v1 = *(const float4*)(xr + 4);
                uint32_t h0 = cvtpk(v0.x, v0.y), h1 = cvtpk(v0.z, v0.w);
                uint32_t h2 = cvtpk(v1.x, v1.y), h3 = cvtpk(v1.z, v1.w);
                uint32_t l0 = cvtpk(v0.x - lof(h0), v0.y - hif(h0));
                uint32_t l1 = cvtpk(v0.z - lof(h1), v0.w - hif(h1));
                uint32_t l2 = cvtpk(v1.x - lof(h2), v1.y - hif(h2));
                uint32_t l3 = cvtpk(v1.z - lof(h3), v1.w - hif(h3));
                FragCvt ch, clo;
                ch.u  = make_uint4(h0, h1, h2, h3);
                clo.u = make_uint4(l0, l1, l2, l3);
                ahi[rt] = ch.f; alo[rt] = clo.f;
            }
            #pragma unroll
            for (int tl = 0; tl < 8; ++tl) {
                const int off = (tl * 16 + cl) * 36 + ks * 16 + rg * 4;
                bf16x8 bhi = *(const bf16x8*)&lds[0][off];
                bf16x8 blo = *(const bf16x8*)&lds[1][off];
                #pragma unroll
                for (int rt = 0; rt < 2; ++rt) {
                    acc[rt][tl] = __builtin_amdgcn_mfma_f32_16x16x32_bf16(alo[rt], bhi, acc[rt][tl], 0, 0, 0);
                    acc[rt][tl] = __builtin_amdgcn_mfma_f32_16x16x32_bf16(ahi[rt], blo, acc[rt][tl], 0, 0, 0);
                    acc[rt][tl] = __builtin_amdgcn_mfma_f32_16x16x32_bf16(ahi[rt], bhi, acc[rt][tl], 0, 0, 0);
                }
            }
        }
    }

    // epilogue: D layout col=cl, rows rg*4+r. Fused a_s/a_d (head = col-tile), bf16 pack.
    #pragma unroll
    for (int rt = 0; rt < 2; ++rt) {
        const int rowb = rowbase + rt * 16 + rg * 4;
        #pragma unroll
        for (int tl = 0; tl < 8; ++tl) {
            f32x4 a = acc[rt][tl];
            float as_ = att_src[tl * 16 + cl], ad_ = att_dst[tl * 16 + cl];
            float s0 = a.x * as_, s1 = a.y * as_, s2 = a.z * as_, s3 = a.w * as_;
            float d0 = a.x * ad_, d1 = a.y * ad_, d2 = a.z * ad_, d3 = a.w * ad_;
            #pragma unroll
            for (int off = 1; off < 16; off <<= 1) {
                s0 += __shfl_xor(s0, off); s1 += __shfl_xor(s1, off);
                s2 += __shfl_xor(s2, off); s3 += __shfl_xor(s3, off);
                d0 += __shfl_xor(d0, off); d1 += __shfl_xor(d1, off);
                d2 += __shfl_xor(d2, off); d3 += __shfl_xor(d3, off);
            }
            float av[4] = {a.x, a.y, a.z, a.w};
            #pragma unroll
            for (int r = 0; r < 4; ++r) {
                float partner = __shfl_xor(av[r], 1);
                if (!(cl & 1)) {
                    int row = rowb + r;
                    if (row < N)
                        h1p[(size_t)row * H1W + tl * 8 + (cl >> 1)] = cvtpk(av[r], partner);
                }
            }
            if (cl == 0) {
                float sv[4] = {s0, s1, s2, s3}, dv[4] = {d0, d1, d2, d3};
                #pragma unroll
                for (int r = 0; r < 4; ++r) {
                    int row = rowb + r;
                    if (row < N) {
                        h1p[(size_t)row * H1W + 64 + tl] = __float_as_uint(sv[r]);
                        ad1[row * 8 + tl] = dv[r];
                    }
                }
            }
        }
    }
}

// ---------------- GEMM2 (MFMA split-precision): h2p = hbuf @ W2, fused a_s2/a_d2 ----------------
__global__ __launch_bounds__(256) void gemm2_mfma(
    const float* __restrict__ h,
    const uint32_t* __restrict__ wthi, const uint32_t* __restrict__ wtlo,
    const float* __restrict__ att_src, const float* __restrict__ att_dst,
    uint32_t* __restrict__ h2p, float* __restrict__ ad2, int N)
{
    __shared__ uint32_t lds[2][64 * 36];
    const int t = threadIdx.x;
    const int w = t >> 6, l = t & 63;
    const int cl = l & 15, rg = l >> 4;
    const int rowbase = blockIdx.x * 128 + w * 32;

    f32x4 zero = {0.f, 0.f, 0.f, 0.f};
    f32x4 acc[2][4];
    #pragma unroll
    for (int rt = 0; rt < 2; ++rt)
        #pragma unroll
        for (int tl = 0; tl < 4; ++tl) acc[rt][tl] = zero;

    for (int kh = 0; kh < 2; ++kh) {
        if (kh) __syncthreads();
        for (int i = t; i < 512; i += 256) {
            int col = i >> 3, q = i & 7;
            *(uint4*)&lds[0][col * 36 + q * 4] = *(const uint4*)&wthi[col * 64 + kh * 32 + q * 4];
            *(uint4*)&lds[1][col * 36 + q * 4] = *(const uint4*)&wtlo[col * 64 + kh * 32 + q * 4];
        }
        __syncthreads();
        #pragma unroll
        for (int ks = 0; ks < 2; ++ks) {
            const int kg = kh * 64 + ks * 32 + rg * 8;
            bf16x8 ahi[2], alo[2];
            #pragma unroll
            for (int rt = 0; rt < 2; ++rt) {
                int row = rowbase + rt * 16 + cl;
                row = min(row, N - 1);
                const float* xr = h + (size_t)row * 128 + kg;
                float4 v0 = *(const float4*)xr;
                float4 v1 = *(const float4*)(xr + 4);
                uint32_t h0 = cvtpk(v0.x, v0.y), h1 = cvtpk(v0.z, v0.w);
                uint32_t h2 = cvtpk(v1.x, v1.y), h3 = cvtpk(v1.z, v1.w);
                uint32_t l0 = cvtpk(v0.x - lof(h0), v0.y - hif(h0));
                uint32_t l1 = cvtpk(v0.z - lof(h1), v0.w - hif(h1));
                uint32_t l2 = cvtpk(v1.x - lof(h2), v1.y - hif(h2));
                uint32_t l3 = cvtpk(v1.z - lof(h3), v1.w - hif(h3));
                FragCvt ch, clo;
                ch.u  = make_uint4(h0, h1, h2, h3);
                clo.u = make_uint4(l0, l1, l2, l3);
                ahi[rt] = ch.f; alo[rt] = clo.f;
            }
            #pragma unroll
            for (int tl = 0; tl < 4; ++tl) {
                const int off = (tl * 16 + cl) * 36 + ks * 16 + rg * 4;
                bf16x8 bhi = *(const bf16x8*)&lds[0][off];
                bf16x8 blo = *(const bf16x8*)&lds[1][off];
                #pragma unroll
                for (int rt = 0; rt < 2; ++rt) {
                    acc[rt][tl] = __builtin_amdgcn_mfma_f32_16x16x32_bf16(alo[rt], bhi, acc[rt][tl], 0, 0, 0);
                    acc[rt][tl] = __builtin_amdgcn_mfma_f32_16x16x32_bf16(ahi[rt], blo, acc[rt][tl], 0, 0, 0);
                    acc[rt][tl] = __builtin_amdgcn_mfma_f32_16x16x32_bf16(ahi[rt], bhi, acc[rt][tl], 0, 0, 0);
                }
            }
        }
    }

    #pragma unroll
    for (int rt = 0; rt < 2; ++rt) {
        const int rowb = rowbase + rt * 16 + rg * 4;
        float s0 = 0.f, s1 = 0.f, s2 = 0.f, s3 = 0.f;
        float d0 = 0.f, d1 = 0.f, d2 = 0.f, d3 = 0.f;
        #pragma unroll
        for (int tl = 0; tl < 4; ++tl) {
            f32x4 a = acc[rt][tl];
            float as_ = att_src[tl * 16 + cl], ad_ = att_dst[tl * 16 + cl];
            s0 += a.x * as_; s1 += a.y * as_; s2 += a.z * as_; s3 += a.w * as_;
            d0 += a.x * ad_; d1 += a.y * ad_; d2 += a.z * ad_; d3 += a.w * ad_;
            float av[4] = {a.x, a.y, a.z, a.w};
            #pragma unroll
            for (int r = 0; r < 4; ++r) {
                float partner = __shfl_xor(av[r], 1);
                if (!(cl & 1)) {
                    int row = rowb + r;
                    if (row < N)
                        h2p[(size_t)row * H2W + tl * 8 + (cl >> 1)] = cvtpk(av[r], partner);
                }
            }
        }
        #pragma unroll
        for (int off = 1; off < 16; off <<= 1) {
            s0 += __shfl_xor(s0, off); s1 += __shfl_xor(s1, off);
            s2 += __shfl_xor(s2, off); s3 += __shfl_xor(s3, off);
            d0 += __shfl_xor(d0, off); d1 += __shfl_xor(d1, off);
            d2 += __shfl_xor(d2, off); d3 += __shfl_xor(d3, off);
        }
        if (cl == 0) {
            float sv[4] = {s0, s1, s2, s3}, dv[4] = {d0, d1, d2, d3};
            #pragma unroll
            for (int r = 0; r < 4; ++r) {
                int row = rowb + r;
                if (row < N) {
                    h2p[(size_t)row * H2W + 32] = __float_as_uint(sv[r]);
                    ad2[row] = dv[r];
                }
            }
        }
    }
}

// ---------------- bucket sort pass 1a: per-block bucket histogram ----------------
__global__ __launch_bounds__(256) void p1_count_kernel(
    const int* __restrict__ ei, int* __restrict__ pbh, int E, int NB, int chunk)
{
    __shared__ int hist[NBMAX];
    int t = threadIdx.x;
    if (t < NB) hist[t] = 0;
    __syncthreads();
    int e0 = blockIdx.x * chunk;
    int e1 = min(E, e0 + chunk);
    for (int e = e0 + t; e < e1; e += 256)
        atomicAdd(&hist[ei[E + e] >> 9], 1);
    __syncthreads();
    if (t < NB) pbh[t * NBLK1 + blockIdx.x] = hist[t];   // bucket-major
}

// ---------------- pass 1b: scan bucket totals; rewrite pbh to absolute bases ----------------
__global__ __launch_bounds__(256) void p1_scan_kernel(
    int* __restrict__ pbh, int* __restrict__ bucket_base, int NB, int E)
{
    __shared__ int ps[256];
    int t = threadIdx.x;
    int s = 0;
    if (t < NB) {
        const int* row = &pbh[t * NBLK1];
        for (int b = 0; b < NBLK1; ++b) s += row[b];
    }
    ps[t] = s; __syncthreads();
    for (int off = 1; off < 256; off <<= 1) {
        int add = (t >= off) ? ps[t - off] : 0;
        __syncthreads();
        ps[t] += add;
        __syncthreads();
    }
    int base = ps[t] - s;   // exclusive
    if (t < NB) {
        bucket_base[t] = base;
        int* row = &pbh[t * NBLK1];
        int run = base;
        for (int b = 0; b < NBLK1; ++b) {
            int c = row[b];
            row[b] = run;
            run += c;
        }
    }
    if (t == 0) bucket_base[NB] = E;
}

// ---------------- pass 1c: place edges into bucket regions (packed src|dst_local) ----------------
__global__ __launch_bounds__(256) void p1_place_kernel(
    const int* __restrict__ ei, const int* __restrict__ pbh,
    uint32_t* __restrict__ staging, int E, int NB, int chunk)
{
    __shared__ int lcur[NBMAX];
    int t = threadIdx.x;
    if (t < NB) lcur[t] = pbh[t * NBLK1 + blockIdx.x];
    __syncthreads();
    int e0 = blockIdx.x * chunk;
    int e1 = min(E, e0 + chunk);
    for (int e = e0 + t; e < e1; e += 256) {
        int s = ei[e], d = ei[E + e];
        int b = d >> 9;
        int p = atomicAdd(&lcur[b], 1);          // LDS atomic
        staging[p] = ((uint32_t)s << 9) | (uint32_t)(d & 511);
    }
}

// ---------------- pass 2: per-bucket CSR build (row_start + sorted_src) ----------------
__global__ __launch_bounds__(256) void p2_build_kernel(
    const uint32_t* __restrict__ staging, const int* __restrict__ bucket_base,
    int* __restrict__ row_start, int* __restrict__ sorted_src, int N, int E, int NB)
{
    __shared__ int cnt[NPB];
    __shared__ int ofs[NPB];
    __shared__ int ps[256];
    int b = blockIdx.x, t = threadIdx.x;
    int base = bucket_base[b], end = bucket_base[b + 1];
    cnt[t] = 0; cnt[t + 256] = 0;
    __syncthreads();
    for (int i = base + t; i < end; i += 256)
        atomicAdd(&cnt[staging[i] & 511], 1);
    __syncthreads();
    int c0 = cnt[2 * t], c1 = cnt[2 * t + 1];
    int p = c0 + c1;
    ps[t] = p; __syncthreads();
    for (int off = 1; off < 256; off <<= 1) {
        int add = (t >= off) ? ps[t - off] : 0;
        __syncthreads();
        ps[t] += add;
        __syncthreads();
    }
    int pex = ps[t] - p;
    ofs[2 * t] = pex;
    ofs[2 * t + 1] = pex + c0;
    __syncthreads();
    int node0 = b * NPB;
    #pragma unroll
    for (int i = t; i < NPB; i += 256) {
        int node = node0 + i;
        if (node < N) row_start[node] = base + ofs[i];
    }
    if (b == NB - 1 && t == 0) row_start[N] = E;
    __syncthreads();
    for (int i = base + t; i < end; i += 256) {
        uint32_t v = staging[i];
        int nl = v & 511;
        int pos = base + atomicAdd(&ofs[nl], 1);   // LDS atomic
        sorted_src[pos] = (int)(v >> 9);
    }
}

// ---------------- gather layer 1 (bf16, lane-specialized weights) ----------------
__global__ __launch_bounds__(256) void gather1_kernel(
    const int* __restrict__ row_start, const int* __restrict__ sorted_src,
    const float* __restrict__ ad1, const uint32_t* __restrict__ h1p,
    const float* __restrict__ b1, float* __restrict__ hbuf, int N)
{
    int node = blockIdx.x * 4 + (threadIdx.x >> 6);
    if (node >= N) return;
    int lane = threadIdx.x & 63;
    int cw = lane;                 // channel-word: channels 2cw, 2cw+1
    int hh = lane >> 3;            // fma-duty head
    int wh = lane & 7;             // weight-duty head
    int r0 = row_start[node], r1 = row_start[node + 1];
    float ad_w = ad1[node * 8 + wh];
    const uint32_t* pch = h1p + cw;
    float acc0 = 0.0f, acc1 = 0.0f, den = 0.0f;

    for (int j = r0; j < r1; j += 8) {
        int jw = j + (lane >> 3);
        bool vw = jw < r1;
        int sw = sorted_src[vw ? jw : r0];
        int swoff = sw * H1W;
        float av = __uint_as_float(h1p[swoff + 64 + wh]);
        float ev = av + ad_w;
        ev = ev > 0.0f ? ev : SLOPE * ev;
        float w = vw ? __expf(ev) : 0.0f;

        #pragma unroll
        for (int k = 0; k < 8; ++k) {
            float wk   = __shfl(w,     k * 8 + hh, 64);
            int   offk = __shfl(swoff, k * 8 + wh, 64);
            uint32_t hv = pch[offk];
            den += wk;
            acc0 = fmaf(wk, __uint_as_float(hv << 16), acc0);
            acc1 = fmaf(wk, __uint_as_float(hv & 0xffff0000u), acc1);
        }
    }
    float inv = 1.0f / (den + EPSV);
    float v0 = acc0 * inv + b1[cw * 2];
    float v1 = acc1 * inv + b1[cw * 2 + 1];
    v0 = v0 > 0.0f ? v0 : expm1f(v0);
    v1 = v1 > 0.0f ? v1 : expm1f(v1);
    *(float2*)&hbuf[(size_t)node * 128 + cw * 2] = make_float2(v0, v1);
}

// ---------------- gather layer 2 (bf16, lane-specialized weights) ----------------
__global__ __launch_bounds__(256) void gather2_kernel(
    const int* __restrict__ row_start, const int* __restrict__ sorted_src,
    const float* __restrict__ ad2, const uint32_t* __restrict__ h2p,
    const float* __restrict__ b2, float* __restrict__ out, int N)
{
    int node = blockIdx.x * 8 + (threadIdx.x >> 5);
    if (node >= N) return;
    int lane = threadIdx.x & 31;
    int cw = lane;
    int r0 = row_start[node], r1 = row_start[node + 1];
    float ad = ad2[node];
    const uint32_t* pch = h2p + cw;
    float acc0 = 0.0f, acc1 = 0.0f, den = 0.0f;

    for (int j = r0; j < r1; j += 8) {
        int jw = j + (lane & 7);
        bool vw = jw < r1;
        int sw = sorted_src[vw ? jw : r0];
        int swoff = sw * H2W;
        float av = __uint_as_float(h2p[swoff + 32]);
        float ev = av + ad;
        ev = ev > 0.0f ? ev : SLOPE * ev;
        float w = vw ? __expf(ev) : 0.0f;

        #pragma unroll
        for (int k = 0; k < 8; ++k) {
            float wk   = __shfl(w,     k, 32);
            int   offk = __shfl(swoff, k, 32);
            uint32_t hv = pch[offk];
            den += wk;
            acc0 = fmaf(wk, __uint_as_float(hv << 16), acc0);
            acc1 = fmaf(wk, __uint_as_float(hv & 0xffff0000u), acc1);
        }
    }
    float inv = 1.0f / (den + EPSV);
    *(float2*)&out[(size_t)node * 64 + cw * 2] =
        make_float2(acc0 * inv + b2[cw * 2], acc1 * inv + b2[cw * 2 + 1]);
}

extern "C" void kernel_launch(void* const* d_in, const int* in_sizes, int n_in,
                              void* d_out, int out_size, void* d_ws, size_t ws_size,
                              hipStream_t stream)
{
    const int N = in_sizes[0] / 128;
    const int E = in_sizes[1] / 2;
    const int NB = (N + NPB - 1) / NPB;
    const int chunk = (E + NBLK1 - 1) / NBLK1;

    const float* x        = (const float*)d_in[0];
    const int*   ei       = (const int*)  d_in[1];
    const float* W1       = (const float*)d_in[2];
    const float* att_src1 = (const float*)d_in[3];
    const float* att_dst1 = (const float*)d_in[4];
    const float* b1       = (const float*)d_in[5];
    const float* W2       = (const float*)d_in[6];
    const float* att_src2 = (const float*)d_in[7];
    const float* att_dst2 = (const float*)d_in[8];
    const float* b2       = (const float*)d_in[9];
    float* out = (float*)d_out;

    uint32_t* h1p  = (uint32_t*)d_ws;                 // N*72 words (reused as h2p N*36)
    float* hbuf    = (float*)(h1p + (size_t)N * H1W); // N*128
    float* ad1     = hbuf + (size_t)N * 128;          // N*8
    float* ad2     = ad1  + (size_t)N * 8;            // N
    int* row_start   = (int*)(ad2 + N);               // N+1
    int* bucket_base = row_start + (N + 1);           // NB+1
    int* pbh         = bucket_base + (NB + 1);        // NB*NBLK1
    int* sorted_src  = pbh + NB * NBLK1;              // E
    uint32_t* staging = (uint32_t*)(sorted_src + E);  // E
    uint32_t* wt1hi = staging + E;                    // 8192
    uint32_t* wt1lo = wt1hi + 128 * 64;               // 8192
    uint32_t* wt2hi = wt1lo + 128 * 64;               // 4096
    uint32_t* wt2lo = wt2hi + 64 * 64;                // 4096
    uint32_t* h2p   = h1p;                            // alias: h1p dead after gather1

    // --- weight prep (bf16 hi/lo transposed tables) ---
    prep_kernel<<<2, 256, 0, stream>>>(W1, W2, wt1hi, wt1lo, wt2hi, wt2lo);

    // --- bucket counting sort by dst (no global atomics) ---
    p1_count_kernel<<<NBLK1, 256, 0, stream>>>(ei, pbh, E, NB, chunk);
    p1_scan_kernel <<<1, 256, 0, stream>>>(pbh, bucket_base, NB, E);
    p1_place_kernel<<<NBLK1, 256, 0, stream>>>(ei, pbh, staging, E, NB, chunk);
    p2_build_kernel<<<NB, 256, 0, stream>>>(staging, bucket_base, row_start, sorted_src, N, E, NB);

    // --- layer 1 ---
    gemm1_mfma<<<(N + 127) / 128, 256, 0, stream>>>(x, wt1hi, wt1lo, att_src1, att_dst1, h1p, ad1, N);
    gather1_kernel<<<(N + 3) / 4, 256, 0, stream>>>(row_start, sorted_src, ad1, h1p, b1, hbuf, N);

    // --- layer 2 ---
    gemm2_mfma<<<(N + 127) / 128, 256, 0, stream>>>(hbuf, wt2hi, wt2lo, att_src2, att_dst2, h2p, ad2, N);
    gather2_kernel<<<(N + 7) / 8, 256, 0, stream>>>(row_start, sorted_src, ad2, h2p, b2, out, N);
}

// Round 8
// 280.135 us; speedup vs baseline: 6.8139x; 1.0035x over previous
//
#include <hip/hip_runtime.h>
#include <hip/hip_bf16.h>
#include <stdint.h>

#define SLOPE 0.2f
#define EPSV 1e-16f
#define H1W 72    // h1p row stride in u32 words: 64 bf16x2 words + 8 fp32 a_src
#define H2W 36    // 32 bf16x2 words + 1 fp32 a_src + 3 pad

#define NPB   512   // nodes per bucket (pow2); bucket = dst >> 9
#define NBMAX 256   // max buckets (N <= 131072)
#define NBLK1 256   // pass-1 blocks

typedef __attribute__((ext_vector_type(8))) short bf16x8;
typedef __attribute__((ext_vector_type(4))) float f32x4;

static __device__ __forceinline__ uint32_t cvtpk(float a, float b) {
    uint32_t r;
    asm("v_cvt_pk_bf16_f32 %0, %1, %2" : "=v"(r) : "v"(a), "v"(b));
    return r;
}
static __device__ __forceinline__ float lof(uint32_t u) { return __uint_as_float(u << 16); }
static __device__ __forceinline__ float hif(uint32_t u) { return __uint_as_float(u & 0xffff0000u); }

union FragCvt { uint4 u; bf16x8 f; };

// ---------------- prep: W1,W2 -> transposed bf16 hi/lo tables WT[n][k] ----------------
__global__ __launch_bounds__(256) void prep_kernel(
    const float* __restrict__ W1, const float* __restrict__ W2,
    uint32_t* __restrict__ wt1hi, uint32_t* __restrict__ wt1lo,
    uint32_t* __restrict__ wt2hi, uint32_t* __restrict__ wt2lo)
{
    int t = threadIdx.x;
    if (blockIdx.x == 0) {
        for (int i = t; i < 128 * 64; i += 256) {
            int n = i >> 6, kp = i & 63;
            float w0 = W1[(2 * kp) * 128 + n], w1 = W1[(2 * kp + 1) * 128 + n];
            uint32_t h = cvtpk(w0, w1);
            wt1hi[n * 64 + kp] = h;
            wt1lo[n * 64 + kp] = cvtpk(w0 - lof(h), w1 - hif(h));
        }
    } else {
        for (int i = t; i < 64 * 64; i += 256) {
            int n = i >> 6, kp = i & 63;
            float w0 = W2[(2 * kp) * 64 + n], w1 = W2[(2 * kp + 1) * 64 + n];
            uint32_t h = cvtpk(w0, w1);
            wt2hi[n * 64 + kp] = h;
            wt2lo[n * 64 + kp] = cvtpk(w0 - lof(h), w1 - hif(h));
        }
    }
}

// ---------------- GEMM1 (MFMA split-precision): h1p = x @ W1, fused a_s/a_d ----------------
__global__ __launch_bounds__(256) void gemm1_mfma(
    const float* __restrict__ x,
    const uint32_t* __restrict__ wthi, const uint32_t* __restrict__ wtlo,
    const float* __restrict__ att_src, const float* __restrict__ att_dst,
    uint32_t* __restrict__ h1p, float* __restrict__ ad1, int N)
{
    __shared__ uint32_t lds[2][128 * 36];
    const int t = threadIdx.x;
    const int w = t >> 6, l = t & 63;
    const int cl = l & 15, rg = l >> 4;
    const int rowbase = blockIdx.x * 128 + w * 32;

    f32x4 zero = {0.f, 0.f, 0.f, 0.f};
    f32x4 acc[2][8];
    #pragma unroll
    for (int rt = 0; rt < 2; ++rt)
        #pragma unroll
        for (int tl = 0; tl < 8; ++tl) acc[rt][tl] = zero;

    for (int kh = 0; kh < 2; ++kh) {
        if (kh) __syncthreads();
        for (int i = t; i < 1024; i += 256) {
            int col = i >> 3, q = i & 7;
            *(uint4*)&lds[0][col * 36 + q * 4] = *(const uint4*)&wthi[col * 64 + kh * 32 + q * 4];
            *(uint4*)&lds[1][col * 36 + q * 4] = *(const uint4*)&wtlo[col * 64 + kh * 32 + q * 4];
        }
        __syncthreads();
        #pragma unroll
        for (int ks = 0; ks < 2; ++ks) {
            const int kg = kh * 64 + ks * 32 + rg * 8;
            bf16x8 ahi[2], alo[2];
            #pragma unroll
            for (int rt = 0; rt < 2; ++rt) {
                int row = rowbase + rt * 16 + cl;
                row = min(row, N - 1);
                const float* xr = x + (size_t)row * 128 + kg;
                float4 v0 = *(const float4*)xr;
                float4 v1 = *(const float4*)(xr + 4);
                uint32_t h0 = cvtpk(v0.x, v0.y), h1 = cvtpk(v0.z, v0.w);
                uint32_t h2 = cvtpk(v1.x, v1.y), h3 = cvtpk(v1.z, v1.w);
                uint32_t l0 = cvtpk(v0.x - lof(h0), v0.y - hif(h0));
                uint32_t l1 = cvtpk(v0.z - lof(h1), v0.w - hif(h1));
                uint32_t l2 = cvtpk(v1.x - lof(h2), v1.y - hif(h2));
                uint32_t l3 = cvtpk(v1.z - lof(h3), v1.w - hif(h3));
                FragCvt ch, clo;
                ch.u  = make_uint4(h0, h1, h2, h3);
                clo.u = make_uint4(l0, l1, l2, l3);
                ahi[rt] = ch.f; alo[rt] = clo.f;
            }
            #pragma unroll
            for (int tl = 0; tl < 8; ++tl) {
                const int off = (tl * 16 + cl) * 36 + ks * 16 + rg * 4;
                bf16x8 bhi = *(const bf16x8*)&lds[0][off];
                bf16x8 blo = *(const bf16x8*)&lds[1][off];
                #pragma unroll
                for (int rt = 0; rt < 2; ++rt) {
                    acc[rt][tl] = __builtin_amdgcn_mfma_f32_16x16x32_bf16(alo[rt], bhi, acc[rt][tl], 0, 0, 0);
                    acc[rt][tl] = __builtin_amdgcn_mfma_f32_16x16x32_bf16(ahi[rt], blo, acc[rt][tl], 0, 0, 0);
                    acc[rt][tl] = __builtin_amdgcn_mfma_f32_16x16x32_bf16(ahi[rt], bhi, acc[rt][tl], 0, 0, 0);
                }
            }
        }
    }

    #pragma unroll
    for (int rt = 0; rt < 2; ++rt) {
        const int rowb = rowbase + rt * 16 + rg * 4;
        #pragma unroll
        for (int tl = 0; tl < 8; ++tl) {
            f32x4 a = acc[rt][tl];
            float as_ = att_src[tl * 16 + cl], ad_ = att_dst[tl * 16 + cl];
            float s0 = a.x * as_, s1 = a.y * as_, s2 = a.z * as_, s3 = a.w * as_;
            float d0 = a.x * ad_, d1 = a.y * ad_, d2 = a.z * ad_, d3 = a.w * ad_;
            #pragma unroll
            for (int off = 1; off < 16; off <<= 1) {
                s0 += __shfl_xor(s0, off); s1 += __shfl_xor(s1, off);
                s2 += __shfl_xor(s2, off); s3 += __shfl_xor(s3, off);
                d0 += __shfl_xor(d0, off); d1 += __shfl_xor(d1, off);
                d2 += __shfl_xor(d2, off); d3 += __shfl_xor(d3, off);
            }
            float av[4] = {a.x, a.y, a.z, a.w};
            #pragma unroll
            for (int r = 0; r < 4; ++r) {
                float partner = __shfl_xor(av[r], 1);
                if (!(cl & 1)) {
                    int row = rowb + r;
                    if (row < N)
                        h1p[(size_t)row * H1W + tl * 8 + (cl >> 1)] = cvtpk(av[r], partner);
                }
            }
            if (cl == 0) {
                float sv[4] = {s0, s1, s2, s3}, dv[4] = {d0, d1, d2, d3};
                #pragma unroll
                for (int r = 0; r < 4; ++r) {
                    int row = rowb + r;
                    if (row < N) {
                        h1p[(size_t)row * H1W + 64 + tl] = __float_as_uint(sv[r]);
                        ad1[row * 8 + tl] = dv[r];
                    }
                }
            }
        }
    }
}

// ---------------- GEMM2 (MFMA split-precision): h2p = hbuf @ W2, fused a_s2/a_d2 ----------------
__global__ __launch_bounds__(256) void gemm2_mfma(
    const float* __restrict__ h,
    const uint32_t* __restrict__ wthi, const uint32_t* __restrict__ wtlo,
    const float* __restrict__ att_src, const float* __restrict__ att_dst,
    uint32_t* __restrict__ h2p, float* __restrict__ ad2, int N)
{
    __shared__ uint32_t lds[2][64 * 36];
    const int t = threadIdx.x;
    const int w = t >> 6, l = t & 63;
    const int cl = l & 15, rg = l >> 4;
    const int rowbase = blockIdx.x * 128 + w * 32;

    f32x4 zero = {0.f, 0.f, 0.f, 0.f};
    f32x4 acc[2][4];
    #pragma unroll
    for (int rt = 0; rt < 2; ++rt)
        #pragma unroll
        for (int tl = 0; tl < 4; ++tl) acc[rt][tl] = zero;

    for (int kh = 0; kh < 2; ++kh) {
        if (kh) __syncthreads();
        for (int i = t; i < 512; i += 256) {
            int col = i >> 3, q = i & 7;
            *(uint4*)&lds[0][col * 36 + q * 4] = *(const uint4*)&wthi[col * 64 + kh * 32 + q * 4];
            *(uint4*)&lds[1][col * 36 + q * 4] = *(const uint4*)&wtlo[col * 64 + kh * 32 + q * 4];
        }
        __syncthreads();
        #pragma unroll
        for (int ks = 0; ks < 2; ++ks) {
            const int kg = kh * 64 + ks * 32 + rg * 8;
            bf16x8 ahi[2], alo[2];
            #pragma unroll
            for (int rt = 0; rt < 2; ++rt) {
                int row = rowbase + rt * 16 + cl;
                row = min(row, N - 1);
                const float* xr = h + (size_t)row * 128 + kg;
                float4 v0 = *(const float4*)xr;
                float4 v1 = *(const float4*)(xr + 4);
                uint32_t h0 = cvtpk(v0.x, v0.y), h1 = cvtpk(v0.z, v0.w);
                uint32_t h2 = cvtpk(v1.x, v1.y), h3 = cvtpk(v1.z, v1.w);
                uint32_t l0 = cvtpk(v0.x - lof(h0), v0.y - hif(h0));
                uint32_t l1 = cvtpk(v0.z - lof(h1), v0.w - hif(h1));
                uint32_t l2 = cvtpk(v1.x - lof(h2), v1.y - hif(h2));
                uint32_t l3 = cvtpk(v1.z - lof(h3), v1.w - hif(h3));
                FragCvt ch, clo;
                ch.u  = make_uint4(h0, h1, h2, h3);
                clo.u = make_uint4(l0, l1, l2, l3);
                ahi[rt] = ch.f; alo[rt] = clo.f;
            }
            #pragma unroll
            for (int tl = 0; tl < 4; ++tl) {
                const int off = (tl * 16 + cl) * 36 + ks * 16 + rg * 4;
                bf16x8 bhi = *(const bf16x8*)&lds[0][off];
                bf16x8 blo = *(const bf16x8*)&lds[1][off];
                #pragma unroll
                for (int rt = 0; rt < 2; ++rt) {
                    acc[rt][tl] = __builtin_amdgcn_mfma_f32_16x16x32_bf16(alo[rt], bhi, acc[rt][tl], 0, 0, 0);
                    acc[rt][tl] = __builtin_amdgcn_mfma_f32_16x16x32_bf16(ahi[rt], blo, acc[rt][tl], 0, 0, 0);
                    acc[rt][tl] = __builtin_amdgcn_mfma_f32_16x16x32_bf16(ahi[rt], bhi, acc[rt][tl], 0, 0, 0);
                }
            }
        }
    }

    #pragma unroll
    for (int rt = 0; rt < 2; ++rt) {
        const int rowb = rowbase + rt * 16 + rg * 4;
        float s0 = 0.f, s1 = 0.f, s2 = 0.f, s3 = 0.f;
        float d0 = 0.f, d1 = 0.f, d2 = 0.f, d3 = 0.f;
        #pragma unroll
        for (int tl = 0; tl < 4; ++tl) {
            f32x4 a = acc[rt][tl];
            float as_ = att_src[tl * 16 + cl], ad_ = att_dst[tl * 16 + cl];
            s0 += a.x * as_; s1 += a.y * as_; s2 += a.z * as_; s3 += a.w * as_;
            d0 += a.x * ad_; d1 += a.y * ad_; d2 += a.z * ad_; d3 += a.w * ad_;
            float av[4] = {a.x, a.y, a.z, a.w};
            #pragma unroll
            for (int r = 0; r < 4; ++r) {
                float partner = __shfl_xor(av[r], 1);
                if (!(cl & 1)) {
                    int row = rowb + r;
                    if (row < N)
                        h2p[(size_t)row * H2W + tl * 8 + (cl >> 1)] = cvtpk(av[r], partner);
                }
            }
        }
        #pragma unroll
        for (int off = 1; off < 16; off <<= 1) {
            s0 += __shfl_xor(s0, off); s1 += __shfl_xor(s1, off);
            s2 += __shfl_xor(s2, off); s3 += __shfl_xor(s3, off);
            d0 += __shfl_xor(d0, off); d1 += __shfl_xor(d1, off);
            d2 += __shfl_xor(d2, off); d3 += __shfl_xor(d3, off);
        }
        if (cl == 0) {
            float sv[4] = {s0, s1, s2, s3}, dv[4] = {d0, d1, d2, d3};
            #pragma unroll
            for (int r = 0; r < 4; ++r) {
                int row = rowb + r;
                if (row < N) {
                    h2p[(size_t)row * H2W + 32] = __float_as_uint(sv[r]);
                    ad2[row] = dv[r];
                }
            }
        }
    }
}

// ---------------- bucket sort pass 1a: per-block bucket histogram ----------------
__global__ __launch_bounds__(256) void p1_count_kernel(
    const int* __restrict__ ei, int* __restrict__ pbh, int E, int NB, int chunk)
{
    __shared__ int hist[NBMAX];
    int t = threadIdx.x;
    if (t < NB) hist[t] = 0;
    __syncthreads();
    int e0 = blockIdx.x * chunk;
    int e1 = min(E, e0 + chunk);
    for (int e = e0 + t; e < e1; e += 256)
        atomicAdd(&hist[ei[E + e] >> 9], 1);
    __syncthreads();
    if (t < NB) pbh[t * NBLK1 + blockIdx.x] = hist[t];   // bucket-major
}

// ---------------- pass 1b: scan bucket totals; rewrite pbh to absolute bases ----------------
__global__ __launch_bounds__(256) void p1_scan_kernel(
    int* __restrict__ pbh, int* __restrict__ bucket_base, int NB, int E)
{
    __shared__ int ps[256];
    int t = threadIdx.x;
    int s = 0;
    if (t < NB) {
        const int* row = &pbh[t * NBLK1];
        for (int b = 0; b < NBLK1; ++b) s += row[b];
    }
    ps[t] = s; __syncthreads();
    for (int off = 1; off < 256; off <<= 1) {
        int add = (t >= off) ? ps[t - off] : 0;
        __syncthreads();
        ps[t] += add;
        __syncthreads();
    }
    int base = ps[t] - s;   // exclusive
    if (t < NB) {
        bucket_base[t] = base;
        int* row = &pbh[t * NBLK1];
        int run = base;
        for (int b = 0; b < NBLK1; ++b) {
            int c = row[b];
            row[b] = run;
            run += c;
        }
    }
    if (t == 0) bucket_base[NB] = E;
}

// ---------------- pass 1c: place edges into bucket regions (packed src|dst_local) ----------------
__global__ __launch_bounds__(256) void p1_place_kernel(
    const int* __restrict__ ei, const int* __restrict__ pbh,
    uint32_t* __restrict__ staging, int E, int NB, int chunk)
{
    __shared__ int lcur[NBMAX];
    int t = threadIdx.x;
    if (t < NB) lcur[t] = pbh[t * NBLK1 + blockIdx.x];
    __syncthreads();
    int e0 = blockIdx.x * chunk;
    int e1 = min(E, e0 + chunk);
    for (int e = e0 + t; e < e1; e += 256) {
        int s = ei[e], d = ei[E + e];
        int b = d >> 9;
        int p = atomicAdd(&lcur[b], 1);          // LDS atomic
        staging[p] = ((uint32_t)s << 9) | (uint32_t)(d & 511);
    }
}

// ---------------- pass 2: per-bucket CSR build (row_start + sorted_src) ----------------
__global__ __launch_bounds__(256) void p2_build_kernel(
    const uint32_t* __restrict__ staging, const int* __restrict__ bucket_base,
    int* __restrict__ row_start, int* __restrict__ sorted_src, int N, int E, int NB)
{
    __shared__ int cnt[NPB];
    __shared__ int ofs[NPB];
    __shared__ int ps[256];
    int b = blockIdx.x, t = threadIdx.x;
    int base = bucket_base[b], end = bucket_base[b + 1];
    cnt[t] = 0; cnt[t + 256] = 0;
    __syncthreads();
    for (int i = base + t; i < end; i += 256)
        atomicAdd(&cnt[staging[i] & 511], 1);
    __syncthreads();
    int c0 = cnt[2 * t], c1 = cnt[2 * t + 1];
    int p = c0 + c1;
    ps[t] = p; __syncthreads();
    for (int off = 1; off < 256; off <<= 1) {
        int add = (t >= off) ? ps[t - off] : 0;
        __syncthreads();
        ps[t] += add;
        __syncthreads();
    }
    int pex = ps[t] - p;
    ofs[2 * t] = pex;
    ofs[2 * t + 1] = pex + c0;
    __syncthreads();
    int node0 = b * NPB;
    #pragma unroll
    for (int i = t; i < NPB; i += 256) {
        int node = node0 + i;
        if (node < N) row_start[node] = base + ofs[i];
    }
    if (b == NB - 1 && t == 0) row_start[N] = E;
    __syncthreads();
    for (int i = base + t; i < end; i += 256) {
        uint32_t v = staging[i];
        int nl = v & 511;
        int pos = base + atomicAdd(&ofs[nl], 1);   // LDS atomic
        sorted_src[pos] = (int)(v >> 9);
    }
}

// ---------------- gather layer 1: 64 lanes/node, 8B gathers, pipelined ----------------
// Phase A: lane l -> weight(edge j+(l>>3), head l&7). Phase B: lanes split in 2
// halves; half p handles edges 2k+p, each lane loads uint2 = 4 channels.
__global__ __launch_bounds__(256) void gather1_kernel(
    const int* __restrict__ row_start, const int* __restrict__ sorted_src,
    const float* __restrict__ ad1, const uint32_t* __restrict__ h1p,
    const float* __restrict__ b1, float* __restrict__ hbuf, int N)
{
    int node = blockIdx.x * 4 + (threadIdx.x >> 6);
    if (node >= N) return;
    const int l   = threadIdx.x & 63;
    const int wh  = l & 7;         // weight-duty head
    const int eA  = l >> 3;        // weight-duty edge slot (0..7)
    const int c4  = l & 31;        // channel group: channels 4*c4..+3
    const int par = l >> 5;        // phase-B parity
    const int hB  = c4 >> 2;       // fma-duty head

    int r0 = row_start[node], r1 = row_start[node + 1];

    if (r0 == r1) {                // isolated node: out = elu(b1)
        if (l < 32) {
            float4 bv = *(const float4*)&b1[c4 * 4];
            bv.x = bv.x > 0.f ? bv.x : expm1f(bv.x);
            bv.y = bv.y > 0.f ? bv.y : expm1f(bv.y);
            bv.z = bv.z > 0.f ? bv.z : expm1f(bv.z);
            bv.w = bv.w > 0.f ? bv.w : expm1f(bv.w);
            *(float4*)&hbuf[(size_t)node * 128 + c4 * 4] = bv;
        }
        return;
    }

    float adw = ad1[node * 8 + wh];
    float acc0 = 0.f, acc1 = 0.f, acc2 = 0.f, acc3 = 0.f, den = 0.f;

    // pipeline prologue: sw for groups 0 and 1; av for group 0
    int jw = r0 + eA;
    int sw0 = sorted_src[jw < r1 ? jw : r0] * H1W;
    int j1 = r0 + 8 + eA;
    int sw1 = sorted_src[j1 < r1 ? j1 : r0] * H1W;
    float av0 = __uint_as_float(h1p[sw0 + 64 + wh]);

    for (int j = r0; j < r1; j += 8) {
        // prefetch sw for group j+16
        int jn = j + 16 + eA;
        int swn = sorted_src[jn < r1 ? jn : r0] * H1W;
        // prefetch av for group j+8
        float avn = __uint_as_float(h1p[sw1 + 64 + wh]);

        // phase A: weight for (edge j+eA, head wh)
        float ev = av0 + adw;
        ev = ev > 0.f ? ev : SLOPE * ev;
        float w = (j + eA) < r1 ? __expf(ev) : 0.f;
        den += w;

        // phase B: 4 iterations x 2 edges
        #pragma unroll
        for (int k = 0; k < 4; ++k) {
            int eidx = 2 * k + par;
            float wk  = __shfl(w,   eidx * 8 + hB, 64);
            int   ofk = __shfl(sw0, eidx * 8,      64);
            uint2 hv = *(const uint2*)&h1p[ofk + 2 * c4];
            acc0 = fmaf(wk, lof(hv.x), acc0);
            acc1 = fmaf(wk, hif(hv.x), acc1);
            acc2 = fmaf(wk, lof(hv.y), acc2);
            acc3 = fmaf(wk, hif(hv.y), acc3);
        }
        sw0 = sw1; sw1 = swn; av0 = avn;
    }

    // den: reduce across the 8 edge-slots (lanes sharing wh)
    den += __shfl_xor(den, 8, 64);
    den += __shfl_xor(den, 16, 64);
    den += __shfl_xor(den, 32, 64);
    float dB = __shfl(den, hB, 64);      // den for fma-duty head

    // merge parity halves
    acc0 += __shfl_xor(acc0, 32, 64);
    acc1 += __shfl_xor(acc1, 32, 64);
    acc2 += __shfl_xor(acc2, 32, 64);
    acc3 += __shfl_xor(acc3, 32, 64);

    if (l < 32) {
        float inv = 1.0f / (dB + EPSV);
        float4 bv = *(const float4*)&b1[c4 * 4];
        float v0 = acc0 * inv + bv.x;
        float v1 = acc1 * inv + bv.y;
        float v2 = acc2 * inv + bv.z;
        float v3 = acc3 * inv + bv.w;
        v0 = v0 > 0.f ? v0 : expm1f(v0);
        v1 = v1 > 0.f ? v1 : expm1f(v1);
        v2 = v2 > 0.f ? v2 : expm1f(v2);
        v3 = v3 > 0.f ? v3 : expm1f(v3);
        *(float4*)&hbuf[(size_t)node * 128 + c4 * 4] = make_float4(v0, v1, v2, v3);
    }
}

// ---------------- gather layer 2: 32 lanes/node, 8B gathers, pipelined ----------------
__global__ __launch_bounds__(256) void gather2_kernel(
    const int* __restrict__ row_start, const int* __restrict__ sorted_src,
    const float* __restrict__ ad2, const uint32_t* __restrict__ h2p,
    const float* __restrict__ b2, float* __restrict__ out, int N)
{
    int node = blockIdx.x * 8 + (threadIdx.x >> 5);
    if (node >= N) return;
    const int l   = threadIdx.x & 31;
    const int eA  = l & 7;         // weight-duty edge slot (4x redundant)
    const int c4  = l & 15;        // channel group: channels 4*c4..+3
    const int par = (l >> 4) & 1;  // phase-B parity

    int r0 = row_start[node], r1 = row_start[node + 1];

    if (r0 == r1) {
        if (l < 16) {
            float4 bv = *(const float4*)&b2[c4 * 4];
            *(float4*)&out[(size_t)node * 64 + c4 * 4] = bv;
        }
        return;
    }

    float ad = ad2[node];
    float acc0 = 0.f, acc1 = 0.f, acc2 = 0.f, acc3 = 0.f, den = 0.f;

    int jw = r0 + eA;
    int sw0 = sorted_src[jw < r1 ? jw : r0] * H2W;
    int j1 = r0 + 8 + eA;
    int sw1 = sorted_src[j1 < r1 ? j1 : r0] * H2W;
    float av0 = __uint_as_float(h2p[sw0 + 32]);

    for (int j = r0; j < r1; j += 8) {
        int jn = j + 16 + eA;
        int swn = sorted_src[jn < r1 ? jn : r0] * H2W;
        float avn = __uint_as_float(h2p[sw1 + 32]);

        float ev = av0 + ad;
        ev = ev > 0.f ? ev : SLOPE * ev;
        float w = (j + eA) < r1 ? __expf(ev) : 0.f;
        den += w;

        #pragma unroll
        for (int k = 0; k < 4; ++k) {
            int eidx = 2 * k + par;
            float wk  = __shfl(w,   eidx, 32);
            int   ofk = __shfl(sw0, eidx, 32);
            uint2 hv = *(const uint2*)&h2p[ofk + 2 * c4];
            acc0 = fmaf(wk, lof(hv.x), acc0);
            acc1 = fmaf(wk, hif(hv.x), acc1);
            acc2 = fmaf(wk, lof(hv.y), acc2);
            acc3 = fmaf(wk, hif(hv.y), acc3);
        }
        sw0 = sw1; sw1 = swn; av0 = avn;
    }

    // den: reduce across edge-slots (bits 0..2)
    den += __shfl_xor(den, 1, 32);
    den += __shfl_xor(den, 2, 32);
    den += __shfl_xor(den, 4, 32);
    // merge parity halves
    acc0 += __shfl_xor(acc0, 16, 32);
    acc1 += __shfl_xor(acc1, 16, 32);
    acc2 += __shfl_xor(acc2, 16, 32);
    acc3 += __shfl_xor(acc3, 16, 32);

    if (l < 16) {
        float inv = 1.0f / (den + EPSV);
        float4 bv = *(const float4*)&b2[c4 * 4];
        *(float4*)&out[(size_t)node * 64 + c4 * 4] =
            make_float4(acc0 * inv + bv.x, acc1 * inv + bv.y,
                        acc2 * inv + bv.z, acc3 * inv + bv.w);
    }
}

extern "C" void kernel_launch(void* const* d_in, const int* in_sizes, int n_in,
                              void* d_out, int out_size, void* d_ws, size_t ws_size,
                              hipStream_t stream)
{
    const int N = in_sizes[0] / 128;
    const int E = in_sizes[1] / 2;
    const int NB = (N + NPB - 1) / NPB;
    const int chunk = (E + NBLK1 - 1) / NBLK1;

    const float* x        = (const float*)d_in[0];
    const int*   ei       = (const int*)  d_in[1];
    const float* W1       = (const float*)d_in[2];
    const float* att_src1 = (const float*)d_in[3];
    const float* att_dst1 = (const float*)d_in[4];
    const float* b1       = (const float*)d_in[5];
    const float* W2       = (const float*)d_in[6];
    const float* att_src2 = (const float*)d_in[7];
    const float* att_dst2 = (const float*)d_in[8];
    const float* b2       = (const float*)d_in[9];
    float* out = (float*)d_out;

    uint32_t* h1p  = (uint32_t*)d_ws;                 // N*72 words (reused as h2p N*36)
    float* hbuf    = (float*)(h1p + (size_t)N * H1W); // N*128
    float* ad1     = hbuf + (size_t)N * 128;          // N*8
    float* ad2     = ad1  + (size_t)N * 8;            // N
    int* row_start   = (int*)(ad2 + N);               // N+1
    int* bucket_base = row_start + (N + 1);           // NB+1
    int* pbh         = bucket_base + (NB + 1);        // NB*NBLK1
    int* sorted_src  = pbh + NB * NBLK1;              // E
    uint32_t* staging = (uint32_t*)(sorted_src + E);  // E
    uint32_t* wt1hi = staging + E;                    // 8192
    uint32_t* wt1lo = wt1hi + 128 * 64;               // 8192
    uint32_t* wt2hi = wt1lo + 128 * 64;               // 4096
    uint32_t* wt2lo = wt2hi + 64 * 64;                // 4096
    uint32_t* h2p   = h1p;                            // alias: h1p dead after gather1

    // --- weight prep (bf16 hi/lo transposed tables) ---
    prep_kernel<<<2, 256, 0, stream>>>(W1, W2, wt1hi, wt1lo, wt2hi, wt2lo);

    // --- bucket counting sort by dst (no global atomics) ---
    p1_count_kernel<<<NBLK1, 256, 0, stream>>>(ei, pbh, E, NB, chunk);
    p1_scan_kernel <<<1, 256, 0, stream>>>(pbh, bucket_base, NB, E);
    p1_place_kernel<<<NBLK1, 256, 0, stream>>>(ei, pbh, staging, E, NB, chunk);
    p2_build_kernel<<<NB, 256, 0, stream>>>(staging, bucket_base, row_start, sorted_src, N, E, NB);

    // --- layer 1 ---
    gemm1_mfma<<<(N + 127) / 128, 256, 0, stream>>>(x, wt1hi, wt1lo, att_src1, att_dst1, h1p, ad1, N);
    gather1_kernel<<<(N + 3) / 4, 256, 0, stream>>>(row_start, sorted_src, ad1, h1p, b1, hbuf, N);

    // --- layer 2 ---
    gemm2_mfma<<<(N + 127) / 128, 256, 0, stream>>>(hbuf, wt2hi, wt2lo, att_src2, att_dst2, h2p, ad2, N);
    gather2_kernel<<<(N + 7) / 8, 256, 0, stream>>>(row_start, sorted_src, ad2, h2p, b2, out, N);
}